// Round 1
// baseline (2229.376 us; speedup 1.0000x reference)
//
#include <hip/hip_runtime.h>
#include <math.h>

#define H 300
#define PP 5
#define CHUNK 48
#define NT 320

__device__ __forceinline__ float wsum64(float v) {
#pragma unroll
    for (int m = 32; m >= 1; m >>= 1) v += __shfl_xor(v, m, 64);
    return v;
}
__device__ __forceinline__ float wmax64(float v) {
#pragma unroll
    for (int m = 32; m >= 1; m >>= 1) v = fmaxf(v, __shfl_xor(v, m, 64));
    return v;
}
__device__ __forceinline__ float eluf(float x) { return x > 0.f ? x : expm1f(x); }

// ---- K1: prop_sim = softmax(instruction @ prop_embeds^T) ; grid=B, block=64
__global__ void k_prop_sim(const float* __restrict__ instr,
                           const float* __restrict__ pe,
                           float* __restrict__ prop_sim) {
    int b = blockIdx.x, lane = threadIdx.x;
    float dots[PP];
#pragma unroll
    for (int p = 0; p < PP; ++p) {
        float s = 0.f;
        for (int hh = lane; hh < H; hh += 64) s += instr[b * H + hh] * pe[p * H + hh];
        dots[p] = wsum64(s);
    }
    if (lane == 0) {
        float m = dots[0];
#pragma unroll
        for (int p = 1; p < PP; ++p) m = fmaxf(m, dots[p]);
        float e[PP], s = 0.f;
#pragma unroll
        for (int p = 0; p < PP; ++p) { e[p] = expf(dots[p] - m); s += e[p]; }
        float inv = 1.f / s;
#pragma unroll
        for (int p = 0; p < PP; ++p) prop_sim[b * PP + p] = e[p] * inv;
    }
}

// ---- K2: histogram of node_indices
__global__ void k_counts(const int* __restrict__ idx, int* __restrict__ counts, int N) {
    int i = blockIdx.x * blockDim.x + threadIdx.x;
    if (i < N) atomicAdd(&counts[idx[i]], 1);
}

// ---- K3: exclusive scan -> segment offsets (B<=256), 1 block of 256
__global__ void k_scan(const int* __restrict__ counts, int* __restrict__ offsets, int B) {
    __shared__ int sh[256];
    int t = threadIdx.x;
    int c = (t < B) ? counts[t] : 0;
    sh[t] = c;
    __syncthreads();
    for (int off = 1; off < 256; off <<= 1) {
        int v = (t >= off) ? sh[t - off] : 0;
        __syncthreads();
        sh[t] += v;
        __syncthreads();
    }
    if (t < B) offsets[t] = sh[t] - c;
    if (t == B - 1) offsets[B] = sh[t];
}

// ---- K4: per-batch node GEMM (combined weights on the fly) + elu + W_state dot
__global__ __launch_bounds__(NT) void k_node(
    const float* __restrict__ na, const float* __restrict__ Ws,
    const float* __restrict__ instr, const float* __restrict__ prop_sim,
    const float* __restrict__ wstate, const int* __restrict__ offsets,
    float* __restrict__ slog)
{
    __shared__ __align__(16) float A_sh[CHUNK * H];
    __shared__ float part_sh[(NT / 64) * CHUNK];
    int b = blockIdx.y;
    int start = offsets[b];
    int len = offsets[b + 1] - start;
    if (len <= 0) return;
    int t = threadIdx.x, wave = t >> 6, lane = t & 63;
    bool hv = t < H;
    int h = hv ? t : 0;
    float ps0 = prop_sim[b * PP + 0], ps1 = prop_sim[b * PP + 1];
    float ps2 = prop_sim[b * PP + 2], ps3 = prop_sim[b * PP + 3];
    float ins = instr[b * H + h];
    float wst = wstate[h];
    const float4* w0 = (const float4*)(Ws + (size_t)(0 * H + h) * H);
    const float4* w1 = (const float4*)(Ws + (size_t)(1 * H + h) * H);
    const float4* w2 = (const float4*)(Ws + (size_t)(2 * H + h) * H);
    const float4* w3 = (const float4*)(Ws + (size_t)(3 * H + h) * H);

    for (int chunk = blockIdx.x; chunk * CHUNK < len; chunk += gridDim.x) {
        int n0 = start + chunk * CHUNK;
        int nn = min(CHUNK, len - chunk * CHUNK);
        __syncthreads();
        {
            const float4* src = (const float4*)(na + (size_t)n0 * H);
            float4* dst = (float4*)A_sh;
            for (int i = t; i < nn * (H / 4); i += NT) dst[i] = src[i];
        }
        __syncthreads();
        float acc[CHUNK];
#pragma unroll
        for (int n = 0; n < CHUNK; ++n) acc[n] = 0.f;
        for (int k4 = 0; k4 < H / 4; ++k4) {
            float4 a0 = w0[k4], a1 = w1[k4], a2 = w2[k4], a3 = w3[k4];
            float c0 = ps0 * a0.x + ps1 * a1.x + ps2 * a2.x + ps3 * a3.x;
            float c1 = ps0 * a0.y + ps1 * a1.y + ps2 * a2.y + ps3 * a3.y;
            float c2 = ps0 * a0.z + ps1 * a1.z + ps2 * a2.z + ps3 * a3.z;
            float c3 = ps0 * a0.w + ps1 * a1.w + ps2 * a2.w + ps3 * a3.w;
#pragma unroll
            for (int n = 0; n < CHUNK; ++n) {
                float4 av = *(const float4*)&A_sh[n * H + k4 * 4];
                acc[n] = fmaf(av.x, c0, acc[n]);
                acc[n] = fmaf(av.y, c1, acc[n]);
                acc[n] = fmaf(av.z, c2, acc[n]);
                acc[n] = fmaf(av.w, c3, acc[n]);
            }
        }
#pragma unroll
        for (int n = 0; n < CHUNK; ++n) {
            float val = hv ? eluf(ins * acc[n]) * wst : 0.f;
            val = wsum64(val);
            if (lane == 0) part_sh[wave * CHUNK + n] = val;
        }
        __syncthreads();
        if (t < nn) {
            float s = 0.f;
#pragma unroll
            for (int w = 0; w < NT / 64; ++w) s += part_sh[w * CHUNK + t];
            slog[n0 + t] = s;
        }
    }
}

// ---- K5: edge GEMM + elu + W_rel dot -> scalar per edge -> atomic scatter
__global__ __launch_bounds__(NT) void k_edge(
    const float* __restrict__ ea, const float* __restrict__ Ws,
    const float* __restrict__ instr, const float* __restrict__ wrel,
    const int* __restrict__ eb, const int* __restrict__ ei,
    const float* __restrict__ dist, float* __restrict__ rlog, int E)
{
    __shared__ __align__(16) float A_sh[CHUNK * H];
    __shared__ float part_sh[(NT / 64) * CHUNK];
    __shared__ int eb_sh[CHUNK];
    int e0 = blockIdx.x * CHUNK;
    int nn = min(CHUNK, E - e0);
    int t = threadIdx.x, wave = t >> 6, lane = t & 63;
    bool hv = t < H;
    int h = hv ? t : 0;
    float wr = wrel[h];
    const float4* w4 = (const float4*)(Ws + (size_t)(4 * H + h) * H);
    if (t < CHUNK) eb_sh[t] = (t < nn) ? eb[e0 + t] : 0;
    {
        const float4* src = (const float4*)(ea + (size_t)e0 * H);
        float4* dst = (float4*)A_sh;
        for (int i = t; i < nn * (H / 4); i += NT) dst[i] = src[i];
    }
    __syncthreads();
    float acc[CHUNK];
#pragma unroll
    for (int n = 0; n < CHUNK; ++n) acc[n] = 0.f;
    for (int k4 = 0; k4 < H / 4; ++k4) {
        float4 wv = w4[k4];
#pragma unroll
        for (int n = 0; n < CHUNK; ++n) {
            float4 av = *(const float4*)&A_sh[n * H + k4 * 4];
            acc[n] = fmaf(av.x, wv.x, acc[n]);
            acc[n] = fmaf(av.y, wv.y, acc[n]);
            acc[n] = fmaf(av.z, wv.z, acc[n]);
            acc[n] = fmaf(av.w, wv.w, acc[n]);
        }
    }
#pragma unroll
    for (int n = 0; n < CHUNK; ++n) {
        float val = 0.f;
        if (hv) {
            float iv = instr[(size_t)eb_sh[n] * H + h];
            val = eluf(iv * acc[n]) * wr;
        }
        val = wsum64(val);
        if (lane == 0) part_sh[wave * CHUNK + n] = val;
    }
    __syncthreads();
    if (t < nn) {
        float s = 0.f;
#pragma unroll
        for (int w = 0; w < NT / 64; ++w) s += part_sh[w * CHUNK + t];
        int e = e0 + t;
        atomicAdd(&rlog[ei[E + e]], dist[ei[e]] * s);
    }
}

// ---- K6: per-batch segment softmax x2 + blend -> next_distribution
__global__ void k_final(const float* __restrict__ slog, const float* __restrict__ rlog,
                        const float* __restrict__ prop_sim, const int* __restrict__ offsets,
                        float* __restrict__ out)
{
    int b = blockIdx.x;
    int s0 = offsets[b], e1 = offsets[b + 1];
    int t = threadIdx.x, wave = t >> 6, lane = t & 63;
    __shared__ float shA[4], shB[4];
    float mS = -3.0e38f, mR = -3.0e38f;
    for (int i = s0 + t; i < e1; i += 256) {
        mS = fmaxf(mS, slog[i]);
        mR = fmaxf(mR, rlog[i]);
    }
    mS = wmax64(mS); mR = wmax64(mR);
    if (lane == 0) { shA[wave] = mS; shB[wave] = mR; }
    __syncthreads();
    mS = fmaxf(fmaxf(shA[0], shA[1]), fmaxf(shA[2], shA[3]));
    mR = fmaxf(fmaxf(shB[0], shB[1]), fmaxf(shB[2], shB[3]));
    __syncthreads();
    float sS = 0.f, sR = 0.f;
    for (int i = s0 + t; i < e1; i += 256) {
        sS += expf(slog[i] - mS);
        sR += expf(rlog[i] - mR);
    }
    sS = wsum64(sS); sR = wsum64(sR);
    if (lane == 0) { shA[wave] = sS; shB[wave] = sR; }
    __syncthreads();
    sS = shA[0] + shA[1] + shA[2] + shA[3];
    sR = shB[0] + shB[1] + shB[2] + shB[3];
    float r = prop_sim[b * PP + (PP - 1)];
    float iS = 1.f / sS, iR = 1.f / sR;
    for (int i = s0 + t; i < e1; i += 256) {
        float ns = expf(slog[i] - mS) * iS;
        float nr = expf(rlog[i] - mR) * iR;
        out[i] = r * nr + (1.f - r) * ns;
    }
}

extern "C" void kernel_launch(void* const* d_in, const int* in_sizes, int n_in,
                              void* d_out, int out_size, void* d_ws, size_t ws_size,
                              hipStream_t stream) {
    (void)n_in; (void)out_size; (void)ws_size;
    const float* instruction  = (const float*)d_in[0];
    const float* distribution = (const float*)d_in[1];
    const float* node_attrs   = (const float*)d_in[2];
    const float* edge_attrs   = (const float*)d_in[3];
    const int*   node_indices = (const int*)d_in[4];
    const int*   edge_batch   = (const int*)d_in[5];
    const int*   edge_indices = (const int*)d_in[6];
    const float* prop_embeds  = (const float*)d_in[7];
    const float* Ws           = (const float*)d_in[8];
    const float* W_state      = (const float*)d_in[9];
    const float* W_rel        = (const float*)d_in[10];

    int B = in_sizes[0] / H;   // 256
    int N = in_sizes[1];       // 51200
    int E = in_sizes[5];       // 102400

    float* out = (float*)d_out;        // [0,N): next_distribution, [N,N+B*PP): prop_sim
    float* prop_sim = out + N;

    float* ws = (float*)d_ws;
    float* state_logits = ws;              // N
    float* rel_logits   = ws + N;          // N
    int*   offsets      = (int*)(ws + 2 * (size_t)N);  // B+1
    int*   counts       = offsets + (B + 1);           // B

    size_t zero_bytes = (size_t)2 * N * sizeof(float) + (size_t)(2 * B + 1) * sizeof(int);
    hipMemsetAsync(d_ws, 0, zero_bytes, stream);

    k_prop_sim<<<B, 64, 0, stream>>>(instruction, prop_embeds, prop_sim);
    k_counts<<<(N + 255) / 256, 256, 0, stream>>>(node_indices, counts, N);
    k_scan<<<1, 256, 0, stream>>>(counts, offsets, B);
    k_node<<<dim3(8, B), NT, 0, stream>>>(node_attrs, Ws, instruction, prop_sim,
                                          W_state, offsets, state_logits);
    k_edge<<<(E + CHUNK - 1) / CHUNK, NT, 0, stream>>>(edge_attrs, Ws, instruction, W_rel,
                                                       edge_batch, edge_indices,
                                                       distribution, rel_logits, E);
    k_final<<<B, 256, 0, stream>>>(state_logits, rel_logits, prop_sim, offsets, out);
}

// Round 2
// 839.908 us; speedup vs baseline: 2.6543x; 2.6543x over previous
//
#include <hip/hip_runtime.h>
#include <math.h>

#define H 300
#define PP 5
#define NTILE 64     // nodes/edges per block tile
#define KT 20        // k-tile
#define KSTEPS 15    // 300/20
#define HTILES 5     // 5 x 64 = 320 padded h
#define NTHREADS 256

__device__ __forceinline__ float wsum64(float v) {
#pragma unroll
    for (int m = 32; m >= 1; m >>= 1) v += __shfl_xor(v, m, 64);
    return v;
}
__device__ __forceinline__ float wmax64(float v) {
#pragma unroll
    for (int m = 32; m >= 1; m >>= 1) v = fmaxf(v, __shfl_xor(v, m, 64));
    return v;
}
__device__ __forceinline__ float eluf(float x) { return x > 0.f ? x : expm1f(x); }

// ---- K1: prop_sim = softmax(instruction @ prop_embeds^T) ; grid=B, block=64
__global__ void k_prop_sim(const float* __restrict__ instr,
                           const float* __restrict__ pe,
                           float* __restrict__ prop_sim) {
    int b = blockIdx.x, lane = threadIdx.x;
    float dots[PP];
#pragma unroll
    for (int p = 0; p < PP; ++p) {
        float s = 0.f;
        for (int hh = lane; hh < H; hh += 64) s += instr[b * H + hh] * pe[p * H + hh];
        dots[p] = wsum64(s);
    }
    if (lane == 0) {
        float m = dots[0];
#pragma unroll
        for (int p = 1; p < PP; ++p) m = fmaxf(m, dots[p]);
        float e[PP], s = 0.f;
#pragma unroll
        for (int p = 0; p < PP; ++p) { e[p] = expf(dots[p] - m); s += e[p]; }
        float inv = 1.f / s;
#pragma unroll
        for (int p = 0; p < PP; ++p) prop_sim[b * PP + p] = e[p] * inv;
    }
}

// ---- K2: histogram of node_indices
__global__ void k_counts(const int* __restrict__ idx, int* __restrict__ counts, int N) {
    int i = blockIdx.x * blockDim.x + threadIdx.x;
    if (i < N) atomicAdd(&counts[idx[i]], 1);
}

// ---- K3: exclusive scan -> segment offsets (B<=256), 1 block of 256
__global__ void k_scan(const int* __restrict__ counts, int* __restrict__ offsets, int B) {
    __shared__ int sh[256];
    int t = threadIdx.x;
    int c = (t < B) ? counts[t] : 0;
    sh[t] = c;
    __syncthreads();
    for (int off = 1; off < 256; off <<= 1) {
        int v = (t >= off) ? sh[t - off] : 0;
        __syncthreads();
        sh[t] += v;
        __syncthreads();
    }
    if (t < B) offsets[t] = sh[t] - c;
    if (t == B - 1) offsets[B] = sh[t];
}

// ======================= node GEMM =======================
// Block: 64 nodes (one tile within one batch) x 320 padded h.
// Threads 16x16: tx -> 4-node quad, ty -> 4-h quad per h-tile.
// LDS: A[KT][64], combined W[KT][320]. acc[5][4][4] in regs.
__global__ __launch_bounds__(NTHREADS, 3) void k_node(
    const float* __restrict__ na, const float* __restrict__ Ws,
    const float* __restrict__ instr, const float* __restrict__ prop_sim,
    const float* __restrict__ wstate, const int* __restrict__ offsets,
    float* __restrict__ slog, int N)
{
    __shared__ __align__(16) float A_sh[KT][NTILE];        // 5 KB
    __shared__ __align__(16) float W_sh[KT][HTILES * 64];  // 25.6 KB
    __shared__ float part_sh[16][NTILE];                   // 4 KB

    int b = blockIdx.y;
    int start = offsets[b];
    int end = offsets[b + 1];
    int n0 = start + blockIdx.x * NTILE;
    if (n0 >= end) return;
    int nn = min(NTILE, end - n0);

    int t = threadIdx.x;
    int tx = t & 15, ty = t >> 4;

    float ps0 = prop_sim[b * PP + 0], ps1 = prop_sim[b * PP + 1];
    float ps2 = prop_sim[b * PP + 2], ps3 = prop_sim[b * PP + 3];

    float acc[HTILES][4][4];
#pragma unroll
    for (int h = 0; h < HTILES; ++h)
#pragma unroll
        for (int i = 0; i < 4; ++i)
#pragma unroll
            for (int j = 0; j < 4; ++j) acc[h][i][j] = 0.f;

    for (int ks = 0; ks < KSTEPS; ++ks) {
        int k0 = ks * KT;
        __syncthreads();
        // stage A: 64 rows x 20 k  (320 float4 jobs)
#pragma unroll
        for (int m = 0; m < 2; ++m) {
            int idx = t + m * NTHREADS;
            if (idx < NTILE * (KT / 4)) {
                int n = idx / (KT / 4), j = idx - n * (KT / 4);
                int nidx = min(n0 + n, N - 1);
                float v[4];
                *(float4*)v = *(const float4*)&na[(size_t)nidx * H + k0 + j * 4];
#pragma unroll
                for (int i = 0; i < 4; ++i) A_sh[j * 4 + i][n] = v[i];
            }
        }
        // stage W combined: 320 h x 20 k (1600 float4 jobs)
#pragma unroll
        for (int m = 0; m < 7; ++m) {
            int idx = t + m * NTHREADS;
            if (idx < HTILES * 64 * (KT / 4)) {
                int h = idx / (KT / 4), j = idx - h * (KT / 4);
                float c[4] = {0.f, 0.f, 0.f, 0.f};
                if (h < H) {
                    size_t base = (size_t)h * H + k0 + j * 4;
                    float w0[4], w1[4], w2[4], w3[4];
                    *(float4*)w0 = *(const float4*)&Ws[0 * (size_t)H * H + base];
                    *(float4*)w1 = *(const float4*)&Ws[1 * (size_t)H * H + base];
                    *(float4*)w2 = *(const float4*)&Ws[2 * (size_t)H * H + base];
                    *(float4*)w3 = *(const float4*)&Ws[3 * (size_t)H * H + base];
#pragma unroll
                    for (int i = 0; i < 4; ++i)
                        c[i] = ps0 * w0[i] + ps1 * w1[i] + ps2 * w2[i] + ps3 * w3[i];
                }
#pragma unroll
                for (int i = 0; i < 4; ++i) W_sh[j * 4 + i][h] = c[i];
            }
        }
        __syncthreads();
        // compute
#pragma unroll
        for (int k = 0; k < KT; ++k) {
            float a[4];
            *(float4*)a = *(const float4*)&A_sh[k][tx * 4];
#pragma unroll
            for (int ht = 0; ht < HTILES; ++ht) {
                float w[4];
                *(float4*)w = *(const float4*)&W_sh[k][ht * 64 + ty * 4];
#pragma unroll
                for (int hi = 0; hi < 4; ++hi)
#pragma unroll
                    for (int ni = 0; ni < 4; ++ni)
                        acc[ht][hi][ni] = fmaf(a[ni], w[hi], acc[ht][hi][ni]);
            }
        }
    }

    // epilogue: logit partial = sum_h wst[h]*elu(ins[h]*dot)
    float pn[4] = {0.f, 0.f, 0.f, 0.f};
    const float* insb = instr + (size_t)b * H;
#pragma unroll
    for (int ht = 0; ht < HTILES; ++ht) {
        int h0 = ht * 64 + ty * 4;
        if (h0 + 3 < H) {
            float iv[4], wv[4];
            *(float4*)iv = *(const float4*)&insb[h0];
            *(float4*)wv = *(const float4*)&wstate[h0];
#pragma unroll
            for (int hi = 0; hi < 4; ++hi)
#pragma unroll
                for (int ni = 0; ni < 4; ++ni)
                    pn[ni] += wv[hi] * eluf(iv[hi] * acc[ht][hi][ni]);
        }
    }
    __syncthreads();
#pragma unroll
    for (int ni = 0; ni < 4; ++ni) part_sh[ty][tx * 4 + ni] = pn[ni];
    __syncthreads();
    if (t < NTILE && t < nn) {
        float s = 0.f;
#pragma unroll
        for (int j = 0; j < 16; ++j) s += part_sh[j][t];
        slog[n0 + t] = s;
    }
}

// ======================= edge GEMM =======================
__global__ __launch_bounds__(NTHREADS, 3) void k_edge(
    const float* __restrict__ ea, const float* __restrict__ Ws,
    const float* __restrict__ instr, const float* __restrict__ wrel,
    const int* __restrict__ eb, const int* __restrict__ ei,
    const float* __restrict__ dist, float* __restrict__ rlog, int E)
{
    __shared__ __align__(16) float A_sh[KT][NTILE];
    __shared__ __align__(16) float W_sh[KT][HTILES * 64];
    __shared__ float part_sh[16][NTILE];

    int e0 = blockIdx.x * NTILE;
    int t = threadIdx.x;
    int tx = t & 15, ty = t >> 4;

    float acc[HTILES][4][4];
#pragma unroll
    for (int h = 0; h < HTILES; ++h)
#pragma unroll
        for (int i = 0; i < 4; ++i)
#pragma unroll
            for (int j = 0; j < 4; ++j) acc[h][i][j] = 0.f;

    const float* W4 = Ws + 4 * (size_t)H * H;

    for (int ks = 0; ks < KSTEPS; ++ks) {
        int k0 = ks * KT;
        __syncthreads();
#pragma unroll
        for (int m = 0; m < 2; ++m) {
            int idx = t + m * NTHREADS;
            if (idx < NTILE * (KT / 4)) {
                int n = idx / (KT / 4), j = idx - n * (KT / 4);
                int eidx = min(e0 + n, E - 1);
                float v[4];
                *(float4*)v = *(const float4*)&ea[(size_t)eidx * H + k0 + j * 4];
#pragma unroll
                for (int i = 0; i < 4; ++i) A_sh[j * 4 + i][n] = v[i];
            }
        }
#pragma unroll
        for (int m = 0; m < 7; ++m) {
            int idx = t + m * NTHREADS;
            if (idx < HTILES * 64 * (KT / 4)) {
                int h = idx / (KT / 4), j = idx - h * (KT / 4);
                float c[4] = {0.f, 0.f, 0.f, 0.f};
                if (h < H)
                    *(float4*)c = *(const float4*)&W4[(size_t)h * H + k0 + j * 4];
#pragma unroll
                for (int i = 0; i < 4; ++i) W_sh[j * 4 + i][h] = c[i];
            }
        }
        __syncthreads();
#pragma unroll
        for (int k = 0; k < KT; ++k) {
            float a[4];
            *(float4*)a = *(const float4*)&A_sh[k][tx * 4];
#pragma unroll
            for (int ht = 0; ht < HTILES; ++ht) {
                float w[4];
                *(float4*)w = *(const float4*)&W_sh[k][ht * 64 + ty * 4];
#pragma unroll
                for (int hi = 0; hi < 4; ++hi)
#pragma unroll
                    for (int ni = 0; ni < 4; ++ni)
                        acc[ht][hi][ni] = fmaf(a[ni], w[hi], acc[ht][hi][ni]);
            }
        }
    }

    // epilogue: per-edge scalar = sum_h wrel[h]*elu(instr[eb[e],h]*dot)
    int be[4];
#pragma unroll
    for (int ni = 0; ni < 4; ++ni) {
        int e = min(e0 + tx * 4 + ni, E - 1);
        be[ni] = eb[e];
    }
    float pe_[4] = {0.f, 0.f, 0.f, 0.f};
#pragma unroll
    for (int ht = 0; ht < HTILES; ++ht) {
        int h0 = ht * 64 + ty * 4;
        if (h0 + 3 < H) {
            float wr[4];
            *(float4*)wr = *(const float4*)&wrel[h0];
#pragma unroll
            for (int ni = 0; ni < 4; ++ni) {
                float iv[4];
                *(float4*)iv = *(const float4*)&instr[(size_t)be[ni] * H + h0];
#pragma unroll
                for (int hi = 0; hi < 4; ++hi)
                    pe_[ni] += wr[hi] * eluf(iv[hi] * acc[ht][hi][ni]);
            }
        }
    }
    __syncthreads();
#pragma unroll
    for (int ni = 0; ni < 4; ++ni) part_sh[ty][tx * 4 + ni] = pe_[ni];
    __syncthreads();
    if (t < NTILE) {
        int e = e0 + t;
        if (e < E) {
            float s = 0.f;
#pragma unroll
            for (int j = 0; j < 16; ++j) s += part_sh[j][t];
            atomicAdd(&rlog[ei[E + e]], dist[ei[e]] * s);
        }
    }
}

// ---- K6: per-batch segment softmax x2 + blend -> next_distribution
__global__ void k_final(const float* __restrict__ slog, const float* __restrict__ rlog,
                        const float* __restrict__ prop_sim, const int* __restrict__ offsets,
                        float* __restrict__ out)
{
    int b = blockIdx.x;
    int s0 = offsets[b], e1 = offsets[b + 1];
    int t = threadIdx.x, wave = t >> 6, lane = t & 63;
    __shared__ float shA[4], shB[4];
    float mS = -3.0e38f, mR = -3.0e38f;
    for (int i = s0 + t; i < e1; i += 256) {
        mS = fmaxf(mS, slog[i]);
        mR = fmaxf(mR, rlog[i]);
    }
    mS = wmax64(mS); mR = wmax64(mR);
    if (lane == 0) { shA[wave] = mS; shB[wave] = mR; }
    __syncthreads();
    mS = fmaxf(fmaxf(shA[0], shA[1]), fmaxf(shA[2], shA[3]));
    mR = fmaxf(fmaxf(shB[0], shB[1]), fmaxf(shB[2], shB[3]));
    __syncthreads();
    float sS = 0.f, sR = 0.f;
    for (int i = s0 + t; i < e1; i += 256) {
        sS += expf(slog[i] - mS);
        sR += expf(rlog[i] - mR);
    }
    sS = wsum64(sS); sR = wsum64(sR);
    if (lane == 0) { shA[wave] = sS; shB[wave] = sR; }
    __syncthreads();
    sS = shA[0] + shA[1] + shA[2] + shA[3];
    sR = shB[0] + shB[1] + shB[2] + shB[3];
    float r = prop_sim[b * PP + (PP - 1)];
    float iS = 1.f / sS, iR = 1.f / sR;
    for (int i = s0 + t; i < e1; i += 256) {
        float ns = expf(slog[i] - mS) * iS;
        float nr = expf(rlog[i] - mR) * iR;
        out[i] = r * nr + (1.f - r) * ns;
    }
}

extern "C" void kernel_launch(void* const* d_in, const int* in_sizes, int n_in,
                              void* d_out, int out_size, void* d_ws, size_t ws_size,
                              hipStream_t stream) {
    (void)n_in; (void)out_size; (void)ws_size;
    const float* instruction  = (const float*)d_in[0];
    const float* distribution = (const float*)d_in[1];
    const float* node_attrs   = (const float*)d_in[2];
    const float* edge_attrs   = (const float*)d_in[3];
    const int*   node_indices = (const int*)d_in[4];
    const int*   edge_batch   = (const int*)d_in[5];
    const int*   edge_indices = (const int*)d_in[6];
    const float* prop_embeds  = (const float*)d_in[7];
    const float* Ws           = (const float*)d_in[8];
    const float* W_state      = (const float*)d_in[9];
    const float* W_rel        = (const float*)d_in[10];

    int B = in_sizes[0] / H;   // 256
    int N = in_sizes[1];       // 51200
    int E = in_sizes[5];       // 102400

    float* out = (float*)d_out;        // [0,N): next_distribution, [N,N+B*PP): prop_sim
    float* prop_sim = out + N;

    float* ws = (float*)d_ws;
    float* state_logits = ws;              // N
    float* rel_logits   = ws + N;          // N
    int*   offsets      = (int*)(ws + 2 * (size_t)N);  // B+1
    int*   counts       = offsets + (B + 1);           // B

    size_t zero_bytes = (size_t)2 * N * sizeof(float) + (size_t)(2 * B + 1) * sizeof(int);
    hipMemsetAsync(d_ws, 0, zero_bytes, stream);

    k_prop_sim<<<B, 64, 0, stream>>>(instruction, prop_embeds, prop_sim);
    k_counts<<<(N + 255) / 256, 256, 0, stream>>>(node_indices, counts, N);
    k_scan<<<1, 256, 0, stream>>>(counts, offsets, B);
    k_node<<<dim3(6, B), NTHREADS, 0, stream>>>(node_attrs, Ws, instruction, prop_sim,
                                                W_state, offsets, state_logits, N);
    k_edge<<<(E + NTILE - 1) / NTILE, NTHREADS, 0, stream>>>(edge_attrs, Ws, instruction,
                                                             W_rel, edge_batch, edge_indices,
                                                             distribution, rel_logits, E);
    k_final<<<B, 256, 0, stream>>>(state_logits, rel_logits, prop_sim, offsets, out);
}

// Round 3
// 584.376 us; speedup vs baseline: 3.8150x; 1.4373x over previous
//
#include <hip/hip_runtime.h>
#include <math.h>

#define H 300
#define PP 5
#define NTILE 64     // nodes/edges per block tile
#define KT 20        // k-tile
#define KSTEPS 15    // 300/20
#define HTILES 5     // 5 x 64 = 320 padded h (global)
#define HT_PER 3     // h-tiles per block (grid.z=2: {0,1,2} and {3,4})
#define APAD 68      // 64 + 4 pad (keeps 16B row alignment, rotates banks)
#define WPAD 196     // 192 + 4 pad
#define NTHREADS 256

__device__ __forceinline__ float wsum64(float v) {
#pragma unroll
    for (int m = 32; m >= 1; m >>= 1) v += __shfl_xor(v, m, 64);
    return v;
}
__device__ __forceinline__ float wmax64(float v) {
#pragma unroll
    for (int m = 32; m >= 1; m >>= 1) v = fmaxf(v, __shfl_xor(v, m, 64));
    return v;
}
__device__ __forceinline__ float eluf(float x) { return x > 0.f ? x : expm1f(x); }

// ---- K1: prop_sim = softmax(instruction @ prop_embeds^T) ; grid=B, block=64
__global__ void k_prop_sim(const float* __restrict__ instr,
                           const float* __restrict__ pe,
                           float* __restrict__ prop_sim) {
    int b = blockIdx.x, lane = threadIdx.x;
    float dots[PP];
#pragma unroll
    for (int p = 0; p < PP; ++p) {
        float s = 0.f;
        for (int hh = lane; hh < H; hh += 64) s += instr[b * H + hh] * pe[p * H + hh];
        dots[p] = wsum64(s);
    }
    if (lane == 0) {
        float m = dots[0];
#pragma unroll
        for (int p = 1; p < PP; ++p) m = fmaxf(m, dots[p]);
        float e[PP], s = 0.f;
#pragma unroll
        for (int p = 0; p < PP; ++p) { e[p] = expf(dots[p] - m); s += e[p]; }
        float inv = 1.f / s;
#pragma unroll
        for (int p = 0; p < PP; ++p) prop_sim[b * PP + p] = e[p] * inv;
    }
}

// ---- K2: histogram of node_indices
__global__ void k_counts(const int* __restrict__ idx, int* __restrict__ counts, int N) {
    int i = blockIdx.x * blockDim.x + threadIdx.x;
    if (i < N) atomicAdd(&counts[idx[i]], 1);
}

// ---- K3: exclusive scan -> segment offsets (B<=256), 1 block of 256
__global__ void k_scan(const int* __restrict__ counts, int* __restrict__ offsets, int B) {
    __shared__ int sh[256];
    int t = threadIdx.x;
    int c = (t < B) ? counts[t] : 0;
    sh[t] = c;
    __syncthreads();
    for (int off = 1; off < 256; off <<= 1) {
        int v = (t >= off) ? sh[t - off] : 0;
        __syncthreads();
        sh[t] += v;
        __syncthreads();
    }
    if (t < B) offsets[t] = sh[t] - c;
    if (t == B - 1) offsets[B] = sh[t];
}

// ======================= node GEMM =======================
// Block: 64 nodes x (<=192) h slice. grid = (ntiles, B, 2).
// Threads 16x16: tx -> 4-node quad, ty -> 4-h quad per h-tile.
// acc[3][4][4] = 48 regs. Partial logits atomicAdd'ed into slog.
__global__ __launch_bounds__(NTHREADS) void k_node(
    const float* __restrict__ na, const float* __restrict__ Ws,
    const float* __restrict__ instr, const float* __restrict__ prop_sim,
    const float* __restrict__ wstate, const int* __restrict__ offsets,
    float* __restrict__ slog, int N)
{
    __shared__ __align__(16) float A_sh[KT][APAD];       // 5.4 KB
    __shared__ __align__(16) float W_sh[KT][WPAD];       // 15.7 KB
    __shared__ float part_sh[16][NTILE];                 // 4 KB

    int b = blockIdx.y;
    int hz = blockIdx.z;                  // 0: tiles 0..2, 1: tiles 3..4
    int ht0 = hz * HT_PER;
    int ht_cnt = min(HT_PER, HTILES - ht0);
    int start = offsets[b];
    int end = offsets[b + 1];
    int n0 = start + blockIdx.x * NTILE;
    if (n0 >= end) return;
    int nn = min(NTILE, end - n0);

    int t = threadIdx.x;
    int tx = t & 15, ty = t >> 4;

    float ps0 = prop_sim[b * PP + 0], ps1 = prop_sim[b * PP + 1];
    float ps2 = prop_sim[b * PP + 2], ps3 = prop_sim[b * PP + 3];

    float acc[HT_PER][4][4];
#pragma unroll
    for (int h = 0; h < HT_PER; ++h)
#pragma unroll
        for (int i = 0; i < 4; ++i)
#pragma unroll
            for (int j = 0; j < 4; ++j) acc[h][i][j] = 0.f;

    int wjobs = ht_cnt * 64 * (KT / 4);

    for (int ks = 0; ks < KSTEPS; ++ks) {
        int k0 = ks * KT;
        __syncthreads();
        // stage A: 64 rows x 20 k  (320 float4 jobs)
#pragma unroll
        for (int m = 0; m < 2; ++m) {
            int idx = t + m * NTHREADS;
            if (idx < NTILE * (KT / 4)) {
                int n = idx / (KT / 4), j = idx - n * (KT / 4);
                int nidx = min(n0 + n, N - 1);
                float v[4];
                *(float4*)v = *(const float4*)&na[(size_t)nidx * H + k0 + j * 4];
#pragma unroll
                for (int i = 0; i < 4; ++i) A_sh[j * 4 + i][n] = v[i];
            }
        }
        // stage W combined: (<=192) h x 20 k
#pragma unroll
        for (int m = 0; m < 4; ++m) {
            int idx = t + m * NTHREADS;
            if (idx < wjobs) {
                int hl = idx / (KT / 4), j = idx - hl * (KT / 4);
                int hg = ht0 * 64 + hl;
                float c[4] = {0.f, 0.f, 0.f, 0.f};
                if (hg < H) {
                    size_t base = (size_t)hg * H + k0 + j * 4;
                    float w0[4], w1[4], w2[4], w3[4];
                    *(float4*)w0 = *(const float4*)&Ws[0 * (size_t)H * H + base];
                    *(float4*)w1 = *(const float4*)&Ws[1 * (size_t)H * H + base];
                    *(float4*)w2 = *(const float4*)&Ws[2 * (size_t)H * H + base];
                    *(float4*)w3 = *(const float4*)&Ws[3 * (size_t)H * H + base];
#pragma unroll
                    for (int i = 0; i < 4; ++i)
                        c[i] = ps0 * w0[i] + ps1 * w1[i] + ps2 * w2[i] + ps3 * w3[i];
                }
#pragma unroll
                for (int i = 0; i < 4; ++i) W_sh[j * 4 + i][hl] = c[i];
            }
        }
        __syncthreads();
        // compute
#pragma unroll
        for (int k = 0; k < KT; ++k) {
            float a[4];
            *(float4*)a = *(const float4*)&A_sh[k][tx * 4];
#pragma unroll
            for (int ht = 0; ht < HT_PER; ++ht) {
                if (ht0 + ht < HTILES) {
                    float w[4];
                    *(float4*)w = *(const float4*)&W_sh[k][ht * 64 + ty * 4];
#pragma unroll
                    for (int hi = 0; hi < 4; ++hi)
#pragma unroll
                        for (int ni = 0; ni < 4; ++ni)
                            acc[ht][hi][ni] = fmaf(a[ni], w[hi], acc[ht][hi][ni]);
                }
            }
        }
    }

    // epilogue: partial logit = sum_{h in slice} wst[h]*elu(ins[h]*dot)
    float pn[4] = {0.f, 0.f, 0.f, 0.f};
    const float* insb = instr + (size_t)b * H;
#pragma unroll
    for (int ht = 0; ht < HT_PER; ++ht) {
        int h0 = (ht0 + ht) * 64 + ty * 4;
        if (ht0 + ht < HTILES && h0 + 3 < H) {
            float iv[4], wv[4];
            *(float4*)iv = *(const float4*)&insb[h0];
            *(float4*)wv = *(const float4*)&wstate[h0];
#pragma unroll
            for (int hi = 0; hi < 4; ++hi)
#pragma unroll
                for (int ni = 0; ni < 4; ++ni)
                    pn[ni] += wv[hi] * eluf(iv[hi] * acc[ht][hi][ni]);
        }
    }
    __syncthreads();
#pragma unroll
    for (int ni = 0; ni < 4; ++ni) part_sh[ty][tx * 4 + ni] = pn[ni];
    __syncthreads();
    if (t < NTILE && t < nn) {
        float s = 0.f;
#pragma unroll
        for (int j = 0; j < 16; ++j) s += part_sh[j][t];
        atomicAdd(&slog[n0 + t], s);
    }
}

// ======================= edge GEMM =======================
// grid = (E/64, 2). Same h-split; per-edge scalar partial atomicAdd'ed.
__global__ __launch_bounds__(NTHREADS) void k_edge(
    const float* __restrict__ ea, const float* __restrict__ Ws,
    const float* __restrict__ instr, const float* __restrict__ wrel,
    const int* __restrict__ eb, const int* __restrict__ ei,
    const float* __restrict__ dist, float* __restrict__ rlog, int E)
{
    __shared__ __align__(16) float A_sh[KT][APAD];
    __shared__ __align__(16) float W_sh[KT][WPAD];
    __shared__ float part_sh[16][NTILE];

    int e0 = blockIdx.x * NTILE;
    int hz = blockIdx.y;
    int ht0 = hz * HT_PER;
    int ht_cnt = min(HT_PER, HTILES - ht0);
    int t = threadIdx.x;
    int tx = t & 15, ty = t >> 4;

    float acc[HT_PER][4][4];
#pragma unroll
    for (int h = 0; h < HT_PER; ++h)
#pragma unroll
        for (int i = 0; i < 4; ++i)
#pragma unroll
            for (int j = 0; j < 4; ++j) acc[h][i][j] = 0.f;

    const float* W4 = Ws + 4 * (size_t)H * H;
    int wjobs = ht_cnt * 64 * (KT / 4);

    for (int ks = 0; ks < KSTEPS; ++ks) {
        int k0 = ks * KT;
        __syncthreads();
#pragma unroll
        for (int m = 0; m < 2; ++m) {
            int idx = t + m * NTHREADS;
            if (idx < NTILE * (KT / 4)) {
                int n = idx / (KT / 4), j = idx - n * (KT / 4);
                int eidx = min(e0 + n, E - 1);
                float v[4];
                *(float4*)v = *(const float4*)&ea[(size_t)eidx * H + k0 + j * 4];
#pragma unroll
                for (int i = 0; i < 4; ++i) A_sh[j * 4 + i][n] = v[i];
            }
        }
#pragma unroll
        for (int m = 0; m < 4; ++m) {
            int idx = t + m * NTHREADS;
            if (idx < wjobs) {
                int hl = idx / (KT / 4), j = idx - hl * (KT / 4);
                int hg = ht0 * 64 + hl;
                float c[4] = {0.f, 0.f, 0.f, 0.f};
                if (hg < H)
                    *(float4*)c = *(const float4*)&W4[(size_t)hg * H + k0 + j * 4];
#pragma unroll
                for (int i = 0; i < 4; ++i) W_sh[j * 4 + i][hl] = c[i];
            }
        }
        __syncthreads();
#pragma unroll
        for (int k = 0; k < KT; ++k) {
            float a[4];
            *(float4*)a = *(const float4*)&A_sh[k][tx * 4];
#pragma unroll
            for (int ht = 0; ht < HT_PER; ++ht) {
                if (ht0 + ht < HTILES) {
                    float w[4];
                    *(float4*)w = *(const float4*)&W_sh[k][ht * 64 + ty * 4];
#pragma unroll
                    for (int hi = 0; hi < 4; ++hi)
#pragma unroll
                        for (int ni = 0; ni < 4; ++ni)
                            acc[ht][hi][ni] = fmaf(a[ni], w[hi], acc[ht][hi][ni]);
                }
            }
        }
    }

    // epilogue: per-edge partial = sum_{h in slice} wrel[h]*elu(instr[eb[e],h]*dot)
    int be[4];
#pragma unroll
    for (int ni = 0; ni < 4; ++ni) {
        int e = min(e0 + tx * 4 + ni, E - 1);
        be[ni] = eb[e];
    }
    float pe_[4] = {0.f, 0.f, 0.f, 0.f};
#pragma unroll
    for (int ht = 0; ht < HT_PER; ++ht) {
        int h0 = (ht0 + ht) * 64 + ty * 4;
        if (ht0 + ht < HTILES && h0 + 3 < H) {
            float wr[4];
            *(float4*)wr = *(const float4*)&wrel[h0];
#pragma unroll
            for (int ni = 0; ni < 4; ++ni) {
                float iv[4];
                *(float4*)iv = *(const float4*)&instr[(size_t)be[ni] * H + h0];
#pragma unroll
                for (int hi = 0; hi < 4; ++hi)
                    pe_[ni] += wr[hi] * eluf(iv[hi] * acc[ht][hi][ni]);
            }
        }
    }
    __syncthreads();
#pragma unroll
    for (int ni = 0; ni < 4; ++ni) part_sh[ty][tx * 4 + ni] = pe_[ni];
    __syncthreads();
    if (t < NTILE) {
        int e = e0 + t;
        if (e < E) {
            float s = 0.f;
#pragma unroll
            for (int j = 0; j < 16; ++j) s += part_sh[j][t];
            atomicAdd(&rlog[ei[E + e]], dist[ei[e]] * s);
        }
    }
}

// ---- K6: per-batch segment softmax x2 + blend -> next_distribution
__global__ void k_final(const float* __restrict__ slog, const float* __restrict__ rlog,
                        const float* __restrict__ prop_sim, const int* __restrict__ offsets,
                        float* __restrict__ out)
{
    int b = blockIdx.x;
    int s0 = offsets[b], e1 = offsets[b + 1];
    int t = threadIdx.x, wave = t >> 6, lane = t & 63;
    __shared__ float shA[4], shB[4];
    float mS = -3.0e38f, mR = -3.0e38f;
    for (int i = s0 + t; i < e1; i += 256) {
        mS = fmaxf(mS, slog[i]);
        mR = fmaxf(mR, rlog[i]);
    }
    mS = wmax64(mS); mR = wmax64(mR);
    if (lane == 0) { shA[wave] = mS; shB[wave] = mR; }
    __syncthreads();
    mS = fmaxf(fmaxf(shA[0], shA[1]), fmaxf(shA[2], shA[3]));
    mR = fmaxf(fmaxf(shB[0], shB[1]), fmaxf(shB[2], shB[3]));
    __syncthreads();
    float sS = 0.f, sR = 0.f;
    for (int i = s0 + t; i < e1; i += 256) {
        sS += expf(slog[i] - mS);
        sR += expf(rlog[i] - mR);
    }
    sS = wsum64(sS); sR = wsum64(sR);
    if (lane == 0) { shA[wave] = sS; shB[wave] = sR; }
    __syncthreads();
    sS = shA[0] + shA[1] + shA[2] + shA[3];
    sR = shB[0] + shB[1] + shB[2] + shB[3];
    float r = prop_sim[b * PP + (PP - 1)];
    float iS = 1.f / sS, iR = 1.f / sR;
    for (int i = s0 + t; i < e1; i += 256) {
        float ns = expf(slog[i] - mS) * iS;
        float nr = expf(rlog[i] - mR) * iR;
        out[i] = r * nr + (1.f - r) * ns;
    }
}

extern "C" void kernel_launch(void* const* d_in, const int* in_sizes, int n_in,
                              void* d_out, int out_size, void* d_ws, size_t ws_size,
                              hipStream_t stream) {
    (void)n_in; (void)out_size; (void)ws_size;
    const float* instruction  = (const float*)d_in[0];
    const float* distribution = (const float*)d_in[1];
    const float* node_attrs   = (const float*)d_in[2];
    const float* edge_attrs   = (const float*)d_in[3];
    const int*   node_indices = (const int*)d_in[4];
    const int*   edge_batch   = (const int*)d_in[5];
    const int*   edge_indices = (const int*)d_in[6];
    const float* prop_embeds  = (const float*)d_in[7];
    const float* Ws           = (const float*)d_in[8];
    const float* W_state      = (const float*)d_in[9];
    const float* W_rel        = (const float*)d_in[10];

    int B = in_sizes[0] / H;   // 256
    int N = in_sizes[1];       // 51200
    int E = in_sizes[5];       // 102400

    float* out = (float*)d_out;        // [0,N): next_distribution, [N,N+B*PP): prop_sim
    float* prop_sim = out + N;

    float* ws = (float*)d_ws;
    float* state_logits = ws;              // N
    float* rel_logits   = ws + N;          // N
    int*   offsets      = (int*)(ws + 2 * (size_t)N);  // B+1
    int*   counts       = offsets + (B + 1);           // B

    size_t zero_bytes = (size_t)2 * N * sizeof(float) + (size_t)(2 * B + 1) * sizeof(int);
    hipMemsetAsync(d_ws, 0, zero_bytes, stream);

    k_prop_sim<<<B, 64, 0, stream>>>(instruction, prop_embeds, prop_sim);
    k_counts<<<(N + 255) / 256, 256, 0, stream>>>(node_indices, counts, N);
    k_scan<<<1, 256, 0, stream>>>(counts, offsets, B);
    k_node<<<dim3(6, B, 2), NTHREADS, 0, stream>>>(node_attrs, Ws, instruction, prop_sim,
                                                   W_state, offsets, state_logits, N);
    k_edge<<<dim3((E + NTILE - 1) / NTILE, 2), NTHREADS, 0, stream>>>(
        edge_attrs, Ws, instruction, W_rel, edge_batch, edge_indices,
        distribution, rel_logits, E);
    k_final<<<B, 256, 0, stream>>>(state_logits, rel_logits, prop_sim, offsets, out);
}

// Round 4
// 540.446 us; speedup vs baseline: 4.1251x; 1.0813x over previous
//
#include <hip/hip_runtime.h>
#include <math.h>

#define H 300
#define KP 320        // padded K
#define PP 5
#define NE 64         // rows (edges/nodes) per block
#define KC 64         // k-chunk (bf16) staged per iteration
#define NCHUNK 5      // 320/64
#define HH 160        // h per block (hz split: 0..159 / 160..319)
#define NHT 10        // 16-h tiles per block
#define NTHREADS 256

using short8 = __attribute__((ext_vector_type(8))) short;
using f32x4  = __attribute__((ext_vector_type(4))) float;

__device__ __forceinline__ float wsum64(float v) {
#pragma unroll
    for (int m = 32; m >= 1; m >>= 1) v += __shfl_xor(v, m, 64);
    return v;
}
__device__ __forceinline__ float wmax64(float v) {
#pragma unroll
    for (int m = 32; m >= 1; m >>= 1) v = fmaxf(v, __shfl_xor(v, m, 64));
    return v;
}
__device__ __forceinline__ float eluf(float x) { return x > 0.f ? x : expm1f(x); }

__device__ __forceinline__ unsigned short f2bf(float x) {
    unsigned int u = __float_as_uint(x);
    unsigned int r = u + 0x7FFF + ((u >> 16) & 1);
    return (unsigned short)(r >> 16);
}
__device__ __forceinline__ float bf2f(unsigned short h) {
    return __uint_as_float(((unsigned int)h) << 16);
}
// swizzled byte offset within a [rows][64 bf16 = 128B] LDS tile
__device__ __forceinline__ int sw(int r, int kb) {
    return r * 128 + (kb ^ ((r & 7) << 4));
}
// split 4 f32 -> packed hi/lo (4 bf16 each as uint2)
__device__ __forceinline__ void split4(const float* v, uint2& ph, uint2& pl) {
    unsigned short hs[4], ls[4];
#pragma unroll
    for (int i = 0; i < 4; ++i) {
        hs[i] = f2bf(v[i]);
        ls[i] = f2bf(v[i] - bf2f(hs[i]));
    }
    ph = make_uint2((unsigned)hs[0] | ((unsigned)hs[1] << 16),
                    (unsigned)hs[2] | ((unsigned)hs[3] << 16));
    pl = make_uint2((unsigned)ls[0] | ((unsigned)ls[1] << 16),
                    (unsigned)ls[2] | ((unsigned)ls[3] << 16));
}

// ---- K1: prop_sim = softmax(instruction @ prop_embeds^T) ; grid=B, block=64
__global__ void k_prop_sim(const float* __restrict__ instr,
                           const float* __restrict__ pe,
                           float* __restrict__ prop_sim) {
    int b = blockIdx.x, lane = threadIdx.x;
    float dots[PP];
#pragma unroll
    for (int p = 0; p < PP; ++p) {
        float s = 0.f;
        for (int hh = lane; hh < H; hh += 64) s += instr[b * H + hh] * pe[p * H + hh];
        dots[p] = wsum64(s);
    }
    if (lane == 0) {
        float m = dots[0];
#pragma unroll
        for (int p = 1; p < PP; ++p) m = fmaxf(m, dots[p]);
        float e[PP], s = 0.f;
#pragma unroll
        for (int p = 0; p < PP; ++p) { e[p] = expf(dots[p] - m); s += e[p]; }
        float inv = 1.f / s;
#pragma unroll
        for (int p = 0; p < PP; ++p) prop_sim[b * PP + p] = e[p] * inv;
    }
}

// ---- K2: histogram of node_indices
__global__ void k_counts(const int* __restrict__ idx, int* __restrict__ counts, int N) {
    int i = blockIdx.x * blockDim.x + threadIdx.x;
    if (i < N) atomicAdd(&counts[idx[i]], 1);
}

// ---- K3: exclusive scan -> segment offsets (B<=256), 1 block of 256
__global__ void k_scan(const int* __restrict__ counts, int* __restrict__ offsets, int B) {
    __shared__ int sh[256];
    int t = threadIdx.x;
    int c = (t < B) ? counts[t] : 0;
    sh[t] = c;
    __syncthreads();
    for (int off = 1; off < 256; off <<= 1) {
        int v = (t >= off) ? sh[t - off] : 0;
        __syncthreads();
        sh[t] += v;
        __syncthreads();
    }
    if (t < B) offsets[t] = sh[t] - c;
    if (t == B - 1) offsets[B] = sh[t];
}

// ---- P1: pre-split W_rel matrix (Ws[4]) into bf16 hi/lo, k padded to 320
__global__ void k_presplit(const float* __restrict__ W4,
                           unsigned short* __restrict__ Whi,
                           unsigned short* __restrict__ Wlo) {
    int h = blockIdx.x, k = threadIdx.x;  // grid 300 x 320
    float x = (k < H) ? W4[h * H + k] : 0.f;
    unsigned short hs = f2bf(x);
    unsigned short ls = f2bf(x - bf2f(hs));
    Whi[h * KP + k] = hs;
    Wlo[h * KP + k] = ls;
}

// ======================= MFMA node GEMM =======================
// grid (6, B, 2). Block: 64 nodes x 160 h. 4 waves x 16 cols x 10 h-tiles.
// D[h, n] via mfma_f32_16x16x32_bf16, bf16x3 split. Epilogue fused.
__global__ __launch_bounds__(NTHREADS) void k_node(
    const float* __restrict__ na, const float* __restrict__ Ws,
    const float* __restrict__ instr, const float* __restrict__ prop_sim,
    const float* __restrict__ wstate, const int* __restrict__ offsets,
    float* __restrict__ slog, int N)
{
    __shared__ unsigned short A_hi[NE * KC], A_lo[NE * KC];     // 8 KB each
    __shared__ unsigned short W_hi[HH * KC], W_lo[HH * KC];     // 20 KB each

    int b = blockIdx.y;
    int hz = blockIdx.z;
    int start = offsets[b];
    int end = offsets[b + 1];
    int n0 = start + blockIdx.x * NE;
    if (n0 >= end) return;
    int nn = min(NE, end - n0);

    int t = threadIdx.x;
    int w = t >> 6, l = t & 63, lane16 = l & 15, g = l >> 4;

    float ps0 = prop_sim[b * PP + 0], ps1 = prop_sim[b * PP + 1];
    float ps2 = prop_sim[b * PP + 2], ps3 = prop_sim[b * PP + 3];

    f32x4 acc[NHT];
#pragma unroll
    for (int ht = 0; ht < NHT; ++ht) acc[ht] = (f32x4){0.f, 0.f, 0.f, 0.f};

    for (int c = 0; c < NCHUNK; ++c) {
        int kc0 = c * KC;
        __syncthreads();
        // stage attrs: 64 rows x 16 quads (f32->split)
#pragma unroll
        for (int m = 0; m < 4; ++m) {
            int idx = t + m * NTHREADS;
            int r = idx >> 4, q = idx & 15;
            int gk = kc0 + q * 4;
            float v[4] = {0.f, 0.f, 0.f, 0.f};
            if (gk < H) {
                int row = min(n0 + r, N - 1);
                *(float4*)v = *(const float4*)&na[(size_t)row * H + gk];
            }
            uint2 ph, pl;
            split4(v, ph, pl);
            *(uint2*)((char*)A_hi + sw(r, q * 8)) = ph;
            *(uint2*)((char*)A_lo + sw(r, q * 8)) = pl;
        }
        // stage combined W: 160 rows x 16 quads (4 mats, combine, split)
#pragma unroll
        for (int m = 0; m < 10; ++m) {
            int idx = t + m * NTHREADS;
            int r = idx >> 4, q = idx & 15;
            int hg = hz * HH + r;
            int gk = kc0 + q * 4;
            float cv[4] = {0.f, 0.f, 0.f, 0.f};
            if (hg < H && gk < H) {
                size_t base = (size_t)hg * H + gk;
                float w0[4], w1[4], w2[4], w3[4];
                *(float4*)w0 = *(const float4*)&Ws[0 * (size_t)H * H + base];
                *(float4*)w1 = *(const float4*)&Ws[1 * (size_t)H * H + base];
                *(float4*)w2 = *(const float4*)&Ws[2 * (size_t)H * H + base];
                *(float4*)w3 = *(const float4*)&Ws[3 * (size_t)H * H + base];
#pragma unroll
                for (int i = 0; i < 4; ++i)
                    cv[i] = fmaf(ps0, w0[i], fmaf(ps1, w1[i], fmaf(ps2, w2[i], ps3 * w3[i])));
            }
            uint2 ph, pl;
            split4(cv, ph, pl);
            *(uint2*)((char*)W_hi + sw(r, q * 8)) = ph;
            *(uint2*)((char*)W_lo + sw(r, q * 8)) = pl;
        }
        __syncthreads();
        // B frags for this wave's 16 node columns
        short8 bh[2], bl[2];
        int brow = (w << 4) + lane16;
#pragma unroll
        for (int kf = 0; kf < 2; ++kf) {
            int kb = kf * 64 + (g << 4);
            bh[kf] = *(const short8*)((const char*)A_hi + sw(brow, kb));
            bl[kf] = *(const short8*)((const char*)A_lo + sw(brow, kb));
        }
#pragma unroll
        for (int ht = 0; ht < NHT; ++ht) {
            int arow = ht * 16 + lane16;
#pragma unroll
            for (int kf = 0; kf < 2; ++kf) {
                int kb = kf * 64 + (g << 4);
                short8 ah = *(const short8*)((const char*)W_hi + sw(arow, kb));
                short8 al = *(const short8*)((const char*)W_lo + sw(arow, kb));
                acc[ht] = __builtin_amdgcn_mfma_f32_16x16x32_bf16(ah, bh[kf], acc[ht], 0, 0, 0);
                acc[ht] = __builtin_amdgcn_mfma_f32_16x16x32_bf16(ah, bl[kf], acc[ht], 0, 0, 0);
                acc[ht] = __builtin_amdgcn_mfma_f32_16x16x32_bf16(al, bh[kf], acc[ht], 0, 0, 0);
            }
        }
    }

    // epilogue: partial logit over this block's 160 h
    int nloc = (w << 4) + lane16;
    const float* insb = instr + (size_t)b * H;
    float part = 0.f;
#pragma unroll
    for (int ht = 0; ht < NHT; ++ht) {
        int hb = hz * HH + ht * 16 + (g << 2);
#pragma unroll
        for (int r = 0; r < 4; ++r) {
            int h = hb + r;
            if (h < H) part += wstate[h] * eluf(insb[h] * acc[ht][r]);
        }
    }
    part += __shfl_xor(part, 16, 64);
    part += __shfl_xor(part, 32, 64);
    if (l < 16 && nloc < nn) atomicAdd(&slog[n0 + nloc], part);
}

// ======================= MFMA edge GEMM =======================
// grid (E/64, 2). Same structure; W pre-split; per-edge scatter epilogue.
__global__ __launch_bounds__(NTHREADS) void k_edge(
    const float* __restrict__ ea,
    const unsigned short* __restrict__ Whi, const unsigned short* __restrict__ Wlo,
    const float* __restrict__ instr, const float* __restrict__ wrel,
    const int* __restrict__ eb, const int* __restrict__ ei,
    const float* __restrict__ dist, float* __restrict__ rlog, int E)
{
    __shared__ unsigned short A_hi[NE * KC], A_lo[NE * KC];
    __shared__ unsigned short W_hi[HH * KC], W_lo[HH * KC];

    int e0 = blockIdx.x * NE;
    int hz = blockIdx.y;
    int t = threadIdx.x;
    int w = t >> 6, l = t & 63, lane16 = l & 15, g = l >> 4;

    f32x4 acc[NHT];
#pragma unroll
    for (int ht = 0; ht < NHT; ++ht) acc[ht] = (f32x4){0.f, 0.f, 0.f, 0.f};

    for (int c = 0; c < NCHUNK; ++c) {
        int kc0 = c * KC;
        __syncthreads();
#pragma unroll
        for (int m = 0; m < 4; ++m) {
            int idx = t + m * NTHREADS;
            int r = idx >> 4, q = idx & 15;
            int gk = kc0 + q * 4;
            float v[4] = {0.f, 0.f, 0.f, 0.f};
            if (gk < H)
                *(float4*)v = *(const float4*)&ea[(size_t)(e0 + r) * H + gk];
            uint2 ph, pl;
            split4(v, ph, pl);
            *(uint2*)((char*)A_hi + sw(r, q * 8)) = ph;
            *(uint2*)((char*)A_lo + sw(r, q * 8)) = pl;
        }
        // stage pre-split W: copy only
#pragma unroll
        for (int m = 0; m < 10; ++m) {
            int idx = t + m * NTHREADS;
            int r = idx >> 4, q = idx & 15;
            int hg = hz * HH + r;
            uint2 ph = make_uint2(0u, 0u), pl = make_uint2(0u, 0u);
            if (hg < H) {
                ph = *(const uint2*)&Whi[(size_t)hg * KP + kc0 + q * 4];
                pl = *(const uint2*)&Wlo[(size_t)hg * KP + kc0 + q * 4];
            }
            *(uint2*)((char*)W_hi + sw(r, q * 8)) = ph;
            *(uint2*)((char*)W_lo + sw(r, q * 8)) = pl;
        }
        __syncthreads();
        short8 bh[2], bl[2];
        int brow = (w << 4) + lane16;
#pragma unroll
        for (int kf = 0; kf < 2; ++kf) {
            int kb = kf * 64 + (g << 4);
            bh[kf] = *(const short8*)((const char*)A_hi + sw(brow, kb));
            bl[kf] = *(const short8*)((const char*)A_lo + sw(brow, kb));
        }
#pragma unroll
        for (int ht = 0; ht < NHT; ++ht) {
            int arow = ht * 16 + lane16;
#pragma unroll
            for (int kf = 0; kf < 2; ++kf) {
                int kb = kf * 64 + (g << 4);
                short8 ah = *(const short8*)((const char*)W_hi + sw(arow, kb));
                short8 al = *(const short8*)((const char*)W_lo + sw(arow, kb));
                acc[ht] = __builtin_amdgcn_mfma_f32_16x16x32_bf16(ah, bh[kf], acc[ht], 0, 0, 0);
                acc[ht] = __builtin_amdgcn_mfma_f32_16x16x32_bf16(ah, bl[kf], acc[ht], 0, 0, 0);
                acc[ht] = __builtin_amdgcn_mfma_f32_16x16x32_bf16(al, bh[kf], acc[ht], 0, 0, 0);
            }
        }
    }

    // epilogue: per-edge scalar partial over this block's 160 h
    int eloc = (w << 4) + lane16;
    int e = e0 + eloc;
    int be = eb[e];
    const float* insb = instr + (size_t)be * H;
    float part = 0.f;
#pragma unroll
    for (int ht = 0; ht < NHT; ++ht) {
        int hb = hz * HH + ht * 16 + (g << 2);
#pragma unroll
        for (int r = 0; r < 4; ++r) {
            int h = hb + r;
            if (h < H) part += wrel[h] * eluf(insb[h] * acc[ht][r]);
        }
    }
    part += __shfl_xor(part, 16, 64);
    part += __shfl_xor(part, 32, 64);
    if (l < 16) atomicAdd(&rlog[ei[E + e]], dist[ei[e]] * part);
}

// ---- K6: per-batch segment softmax x2 + blend -> next_distribution
__global__ void k_final(const float* __restrict__ slog, const float* __restrict__ rlog,
                        const float* __restrict__ prop_sim, const int* __restrict__ offsets,
                        float* __restrict__ out)
{
    int b = blockIdx.x;
    int s0 = offsets[b], e1 = offsets[b + 1];
    int t = threadIdx.x, wave = t >> 6, lane = t & 63;
    __shared__ float shA[4], shB[4];
    float mS = -3.0e38f, mR = -3.0e38f;
    for (int i = s0 + t; i < e1; i += 256) {
        mS = fmaxf(mS, slog[i]);
        mR = fmaxf(mR, rlog[i]);
    }
    mS = wmax64(mS); mR = wmax64(mR);
    if (lane == 0) { shA[wave] = mS; shB[wave] = mR; }
    __syncthreads();
    mS = fmaxf(fmaxf(shA[0], shA[1]), fmaxf(shA[2], shA[3]));
    mR = fmaxf(fmaxf(shB[0], shB[1]), fmaxf(shB[2], shB[3]));
    __syncthreads();
    float sS = 0.f, sR = 0.f;
    for (int i = s0 + t; i < e1; i += 256) {
        sS += expf(slog[i] - mS);
        sR += expf(rlog[i] - mR);
    }
    sS = wsum64(sS); sR = wsum64(sR);
    if (lane == 0) { shA[wave] = sS; shB[wave] = sR; }
    __syncthreads();
    sS = shA[0] + shA[1] + shA[2] + shA[3];
    sR = shB[0] + shB[1] + shB[2] + shB[3];
    float r = prop_sim[b * PP + (PP - 1)];
    float iS = 1.f / sS, iR = 1.f / sR;
    for (int i = s0 + t; i < e1; i += 256) {
        float ns = expf(slog[i] - mS) * iS;
        float nr = expf(rlog[i] - mR) * iR;
        out[i] = r * nr + (1.f - r) * ns;
    }
}

extern "C" void kernel_launch(void* const* d_in, const int* in_sizes, int n_in,
                              void* d_out, int out_size, void* d_ws, size_t ws_size,
                              hipStream_t stream) {
    (void)n_in; (void)out_size; (void)ws_size;
    const float* instruction  = (const float*)d_in[0];
    const float* distribution = (const float*)d_in[1];
    const float* node_attrs   = (const float*)d_in[2];
    const float* edge_attrs   = (const float*)d_in[3];
    const int*   node_indices = (const int*)d_in[4];
    const int*   edge_batch   = (const int*)d_in[5];
    const int*   edge_indices = (const int*)d_in[6];
    const float* prop_embeds  = (const float*)d_in[7];
    const float* Ws           = (const float*)d_in[8];
    const float* W_state      = (const float*)d_in[9];
    const float* W_rel        = (const float*)d_in[10];

    int B = in_sizes[0] / H;   // 256
    int N = in_sizes[1];       // 51200
    int E = in_sizes[5];       // 102400

    float* out = (float*)d_out;        // [0,N): next_distribution, [N,N+B*PP): prop_sim
    float* prop_sim = out + N;

    float* ws = (float*)d_ws;
    float* state_logits = ws;                          // N
    float* rel_logits   = ws + N;                      // N
    int*   offsets      = (int*)(ws + 2 * (size_t)N);  // B+1
    int*   counts       = offsets + (B + 1);           // B
    uintptr_t wsp = (uintptr_t)(counts + B);
    wsp = (wsp + 15) & ~(uintptr_t)15;
    unsigned short* Whi = (unsigned short*)wsp;        // 300*320 bf16
    unsigned short* Wlo = Whi + (size_t)H * KP;

    size_t zero_bytes = (size_t)2 * N * sizeof(float) + (size_t)(2 * B + 1) * sizeof(int);
    hipMemsetAsync(d_ws, 0, zero_bytes, stream);

    k_presplit<<<H, KP, 0, stream>>>(Ws + 4 * (size_t)H * H, Whi, Wlo);
    k_prop_sim<<<B, 64, 0, stream>>>(instruction, prop_embeds, prop_sim);
    k_counts<<<(N + 255) / 256, 256, 0, stream>>>(node_indices, counts, N);
    k_scan<<<1, 256, 0, stream>>>(counts, offsets, B);
    k_node<<<dim3(6, B, 2), NTHREADS, 0, stream>>>(node_attrs, Ws, instruction, prop_sim,
                                                   W_state, offsets, state_logits, N);
    k_edge<<<dim3(E / NE, 2), NTHREADS, 0, stream>>>(edge_attrs, Whi, Wlo, instruction,
                                                     W_rel, edge_batch, edge_indices,
                                                     distribution, rel_logits, E);
    k_final<<<B, 256, 0, stream>>>(state_logits, rel_logits, prop_sim, offsets, out);
}

// Round 5
// 427.457 us; speedup vs baseline: 5.2154x; 1.2643x over previous
//
#include <hip/hip_runtime.h>
#include <math.h>

#define H 300
#define KP 320        // padded K
#define PP 5
#define NE 64         // rows (edges/nodes) per block
#define KC 64         // k-chunk (bf16) staged per iteration
#define NCHUNK 5      // 320/64
#define HH 160        // h per block (hz split: 0..159 / 160..319)
#define NHT 10        // 16-h tiles per block
#define NTHREADS 256

using short8 = __attribute__((ext_vector_type(8))) short;
using f32x4  = __attribute__((ext_vector_type(4))) float;

__device__ __forceinline__ float wsum64(float v) {
#pragma unroll
    for (int m = 32; m >= 1; m >>= 1) v += __shfl_xor(v, m, 64);
    return v;
}
__device__ __forceinline__ float wmax64(float v) {
#pragma unroll
    for (int m = 32; m >= 1; m >>= 1) v = fmaxf(v, __shfl_xor(v, m, 64));
    return v;
}
__device__ __forceinline__ float eluf(float x) { return x > 0.f ? x : expm1f(x); }

__device__ __forceinline__ unsigned short f2bf(float x) {
    unsigned int u = __float_as_uint(x);
    unsigned int r = u + 0x7FFF + ((u >> 16) & 1);
    return (unsigned short)(r >> 16);
}
__device__ __forceinline__ float bf2f(unsigned short h) {
    return __uint_as_float(((unsigned int)h) << 16);
}
// swizzled byte offset within a [rows][64 bf16 = 128B] LDS tile
__device__ __forceinline__ int sw(int r, int kb) {
    return r * 128 + (kb ^ ((r & 7) << 4));
}
// split 4 f32 -> packed hi/lo (4 bf16 each as uint2)
__device__ __forceinline__ void split4(const float* v, uint2& ph, uint2& pl) {
    unsigned short hs[4], ls[4];
#pragma unroll
    for (int i = 0; i < 4; ++i) {
        hs[i] = f2bf(v[i]);
        ls[i] = f2bf(v[i] - bf2f(hs[i]));
    }
    ph = make_uint2((unsigned)hs[0] | ((unsigned)hs[1] << 16),
                    (unsigned)hs[2] | ((unsigned)hs[3] << 16));
    pl = make_uint2((unsigned)ls[0] | ((unsigned)ls[1] << 16),
                    (unsigned)ls[2] | ((unsigned)ls[3] << 16));
}

// ---- K1: prop_sim = softmax(instruction @ prop_embeds^T) ; grid=B, block=64
__global__ void k_prop_sim(const float* __restrict__ instr,
                           const float* __restrict__ pe,
                           float* __restrict__ prop_sim) {
    int b = blockIdx.x, lane = threadIdx.x;
    float dots[PP];
#pragma unroll
    for (int p = 0; p < PP; ++p) {
        float s = 0.f;
        for (int hh = lane; hh < H; hh += 64) s += instr[b * H + hh] * pe[p * H + hh];
        dots[p] = wsum64(s);
    }
    if (lane == 0) {
        float m = dots[0];
#pragma unroll
        for (int p = 1; p < PP; ++p) m = fmaxf(m, dots[p]);
        float e[PP], s = 0.f;
#pragma unroll
        for (int p = 0; p < PP; ++p) { e[p] = expf(dots[p] - m); s += e[p]; }
        float inv = 1.f / s;
#pragma unroll
        for (int p = 0; p < PP; ++p) prop_sim[b * PP + p] = e[p] * inv;
    }
}

// ---- K2: histogram of node_indices
__global__ void k_counts(const int* __restrict__ idx, int* __restrict__ counts, int N) {
    int i = blockIdx.x * blockDim.x + threadIdx.x;
    if (i < N) atomicAdd(&counts[idx[i]], 1);
}

// ---- K3: exclusive scan -> segment offsets (B<=256), 1 block of 256
__global__ void k_scan(const int* __restrict__ counts, int* __restrict__ offsets, int B) {
    __shared__ int sh[256];
    int t = threadIdx.x;
    int c = (t < B) ? counts[t] : 0;
    sh[t] = c;
    __syncthreads();
    for (int off = 1; off < 256; off <<= 1) {
        int v = (t >= off) ? sh[t - off] : 0;
        __syncthreads();
        sh[t] += v;
        __syncthreads();
    }
    if (t < B) offsets[t] = sh[t] - c;
    if (t == B - 1) offsets[B] = sh[t];
}

// ---- P1: pre-split W_rel matrix (Ws[4]) into bf16 hi/lo, k padded to 320
__global__ void k_presplit(const float* __restrict__ W4,
                           unsigned short* __restrict__ Whi,
                           unsigned short* __restrict__ Wlo) {
    int h = blockIdx.x, k = threadIdx.x;  // grid 300 x 320
    float x = (k < H) ? W4[h * H + k] : 0.f;
    unsigned short hs = f2bf(x);
    unsigned short ls = f2bf(x - bf2f(hs));
    Whi[h * KP + k] = hs;
    Wlo[h * KP + k] = ls;
}

// ======================= MFMA node GEMM (T14 pipelined) =======================
// grid (6, B, 2). Block: 64 nodes x 160 h. 4 waves x 16 cols x 10 h-tiles.
__global__ __launch_bounds__(NTHREADS) void k_node(
    const float* __restrict__ na, const float* __restrict__ Ws,
    const float* __restrict__ instr, const float* __restrict__ prop_sim,
    const float* __restrict__ wstate, const int* __restrict__ offsets,
    float* __restrict__ slog, int N)
{
    __shared__ unsigned short A_hi[NE * KC], A_lo[NE * KC];     // 8 KB each
    __shared__ unsigned short W_hi[HH * KC], W_lo[HH * KC];     // 20 KB each

    int b = blockIdx.y;
    int hz = blockIdx.z;
    int start = offsets[b];
    int end = offsets[b + 1];
    int n0 = start + blockIdx.x * NE;
    if (n0 >= end) return;
    int nn = min(NE, end - n0);

    int t = threadIdx.x;
    int w = t >> 6, l = t & 63, lane16 = l & 15, g = l >> 4;
    int r0 = t >> 4, q = t & 15;          // job coords: rows r0+16m, k-quad q

    float ps0 = prop_sim[b * PP + 0], ps1 = prop_sim[b * PP + 1];
    float ps2 = prop_sim[b * PP + 2], ps3 = prop_sim[b * PP + 3];

    f32x4 acc[NHT];
#pragma unroll
    for (int ht = 0; ht < NHT; ++ht) acc[ht] = (f32x4){0.f, 0.f, 0.f, 0.f};

    float4 pa[4];   // prefetched A quads (chunk in flight)

    auto loadA = [&](int c) {
        int gk = c * KC + q * 4;
#pragma unroll
        for (int m = 0; m < 4; ++m) {
            float4 v = {0.f, 0.f, 0.f, 0.f};
            if (gk < H) {
                int row = min(n0 + r0 + 16 * m, N - 1);
                v = *(const float4*)&na[(size_t)row * H + gk];
            }
            pa[m] = v;
        }
    };
    auto storeA = [&]() {
#pragma unroll
        for (int m = 0; m < 4; ++m) {
            float v[4] = {pa[m].x, pa[m].y, pa[m].z, pa[m].w};
            uint2 ph, pl;
            split4(v, ph, pl);
            int r = r0 + 16 * m;
            *(uint2*)((char*)A_hi + sw(r, q * 8)) = ph;
            *(uint2*)((char*)A_lo + sw(r, q * 8)) = pl;
        }
    };
    // W combine from 4 matrices (L2-resident), split, write. Not reg-prefetched.
    auto stageW = [&](int c) {
        int gk = c * KC + q * 4;
#pragma unroll
        for (int m = 0; m < 10; ++m) {
            int r = r0 + 16 * m;
            int hg = hz * HH + r;
            float cv[4] = {0.f, 0.f, 0.f, 0.f};
            if (hg < H && gk < H) {
                size_t base = (size_t)hg * H + gk;
                float w0[4], w1[4], w2[4], w3[4];
                *(float4*)w0 = *(const float4*)&Ws[0 * (size_t)H * H + base];
                *(float4*)w1 = *(const float4*)&Ws[1 * (size_t)H * H + base];
                *(float4*)w2 = *(const float4*)&Ws[2 * (size_t)H * H + base];
                *(float4*)w3 = *(const float4*)&Ws[3 * (size_t)H * H + base];
#pragma unroll
                for (int i = 0; i < 4; ++i)
                    cv[i] = fmaf(ps0, w0[i], fmaf(ps1, w1[i], fmaf(ps2, w2[i], ps3 * w3[i])));
            }
            uint2 ph, pl;
            split4(cv, ph, pl);
            *(uint2*)((char*)W_hi + sw(r, q * 8)) = ph;
            *(uint2*)((char*)W_lo + sw(r, q * 8)) = pl;
        }
    };

    // prologue: stage chunk 0, issue loads for chunk 1
    loadA(0);
    storeA();
    stageW(0);
    loadA(1);
    __syncthreads();

    for (int c = 0; c < NCHUNK; ++c) {
        // ---- compute chunk c ----
        int brow = (w << 4) + lane16;
        short8 bh[2], bl[2];
#pragma unroll
        for (int kf = 0; kf < 2; ++kf) {
            int kb = kf * 64 + (g << 4);
            bh[kf] = *(const short8*)((const char*)A_hi + sw(brow, kb));
            bl[kf] = *(const short8*)((const char*)A_lo + sw(brow, kb));
        }
#pragma unroll
        for (int ht = 0; ht < NHT; ++ht) {
            int arow = ht * 16 + lane16;
#pragma unroll
            for (int kf = 0; kf < 2; ++kf) {
                int kb = kf * 64 + (g << 4);
                short8 ah = *(const short8*)((const char*)W_hi + sw(arow, kb));
                short8 al = *(const short8*)((const char*)W_lo + sw(arow, kb));
                acc[ht] = __builtin_amdgcn_mfma_f32_16x16x32_bf16(ah, bh[kf], acc[ht], 0, 0, 0);
                acc[ht] = __builtin_amdgcn_mfma_f32_16x16x32_bf16(ah, bl[kf], acc[ht], 0, 0, 0);
                acc[ht] = __builtin_amdgcn_mfma_f32_16x16x32_bf16(al, bh[kf], acc[ht], 0, 0, 0);
            }
        }
        __syncthreads();
        // ---- stage chunk c+1 (regs -> LDS), issue loads for c+2 ----
        if (c + 1 < NCHUNK) {
            storeA();                       // consumes pa (chunk c+1)
            if (c + 2 < NCHUNK) loadA(c + 2);  // in flight across next compute
            stageW(c + 1);
            __syncthreads();
        }
    }

    // epilogue: partial logit over this block's 160 h
    int nloc = (w << 4) + lane16;
    const float* insb = instr + (size_t)b * H;
    float part = 0.f;
#pragma unroll
    for (int ht = 0; ht < NHT; ++ht) {
        int hb = hz * HH + ht * 16 + (g << 2);
#pragma unroll
        for (int r = 0; r < 4; ++r) {
            int h = hb + r;
            if (h < H) part += wstate[h] * eluf(insb[h] * acc[ht][r]);
        }
    }
    part += __shfl_xor(part, 16, 64);
    part += __shfl_xor(part, 32, 64);
    if (l < 16 && nloc < nn) atomicAdd(&slog[n0 + nloc], part);
}

// ======================= MFMA edge GEMM (T14 pipelined) =======================
// grid (E/64, 2). W pre-split (A and W both reg-prefetched one chunk ahead).
__global__ __launch_bounds__(NTHREADS) void k_edge(
    const float* __restrict__ ea,
    const unsigned short* __restrict__ Whi, const unsigned short* __restrict__ Wlo,
    const float* __restrict__ instr, const float* __restrict__ wrel,
    const int* __restrict__ eb, const int* __restrict__ ei,
    const float* __restrict__ dist, float* __restrict__ rlog, int E)
{
    __shared__ unsigned short A_hi[NE * KC], A_lo[NE * KC];
    __shared__ unsigned short W_hi[HH * KC], W_lo[HH * KC];

    int e0 = blockIdx.x * NE;
    int hz = blockIdx.y;
    int t = threadIdx.x;
    int w = t >> 6, l = t & 63, lane16 = l & 15, g = l >> 4;
    int r0 = t >> 4, q = t & 15;

    f32x4 acc[NHT];
#pragma unroll
    for (int ht = 0; ht < NHT; ++ht) acc[ht] = (f32x4){0.f, 0.f, 0.f, 0.f};

    float4 pa[4];
    uint2 pwh[10], pwl[10];

    auto loadA = [&](int c) {
        int gk = c * KC + q * 4;
#pragma unroll
        for (int m = 0; m < 4; ++m) {
            float4 v = {0.f, 0.f, 0.f, 0.f};
            if (gk < H)
                v = *(const float4*)&ea[(size_t)(e0 + r0 + 16 * m) * H + gk];
            pa[m] = v;
        }
    };
    auto loadW = [&](int c) {
        int gk = c * KC + q * 4;   // < 320 always; rows padded via hg guard
#pragma unroll
        for (int m = 0; m < 10; ++m) {
            int hg = hz * HH + r0 + 16 * m;
            uint2 ph = make_uint2(0u, 0u), pl = make_uint2(0u, 0u);
            if (hg < H) {
                ph = *(const uint2*)&Whi[(size_t)hg * KP + gk];
                pl = *(const uint2*)&Wlo[(size_t)hg * KP + gk];
            }
            pwh[m] = ph;
            pwl[m] = pl;
        }
    };
    auto storeA = [&]() {
#pragma unroll
        for (int m = 0; m < 4; ++m) {
            float v[4] = {pa[m].x, pa[m].y, pa[m].z, pa[m].w};
            uint2 ph, pl;
            split4(v, ph, pl);
            int r = r0 + 16 * m;
            *(uint2*)((char*)A_hi + sw(r, q * 8)) = ph;
            *(uint2*)((char*)A_lo + sw(r, q * 8)) = pl;
        }
    };
    auto storeW = [&]() {
#pragma unroll
        for (int m = 0; m < 10; ++m) {
            int r = r0 + 16 * m;
            *(uint2*)((char*)W_hi + sw(r, q * 8)) = pwh[m];
            *(uint2*)((char*)W_lo + sw(r, q * 8)) = pwl[m];
        }
    };

    loadA(0); loadW(0);
    storeA(); storeW();
    loadA(1); loadW(1);
    __syncthreads();

    for (int c = 0; c < NCHUNK; ++c) {
        int brow = (w << 4) + lane16;
        short8 bh[2], bl[2];
#pragma unroll
        for (int kf = 0; kf < 2; ++kf) {
            int kb = kf * 64 + (g << 4);
            bh[kf] = *(const short8*)((const char*)A_hi + sw(brow, kb));
            bl[kf] = *(const short8*)((const char*)A_lo + sw(brow, kb));
        }
#pragma unroll
        for (int ht = 0; ht < NHT; ++ht) {
            int arow = ht * 16 + lane16;
#pragma unroll
            for (int kf = 0; kf < 2; ++kf) {
                int kb = kf * 64 + (g << 4);
                short8 ah = *(const short8*)((const char*)W_hi + sw(arow, kb));
                short8 al = *(const short8*)((const char*)W_lo + sw(arow, kb));
                acc[ht] = __builtin_amdgcn_mfma_f32_16x16x32_bf16(ah, bh[kf], acc[ht], 0, 0, 0);
                acc[ht] = __builtin_amdgcn_mfma_f32_16x16x32_bf16(ah, bl[kf], acc[ht], 0, 0, 0);
                acc[ht] = __builtin_amdgcn_mfma_f32_16x16x32_bf16(al, bh[kf], acc[ht], 0, 0, 0);
            }
        }
        __syncthreads();
        if (c + 1 < NCHUNK) {
            storeA(); storeW();                 // consume prefetched chunk c+1
            if (c + 2 < NCHUNK) { loadA(c + 2); loadW(c + 2); }
            __syncthreads();
        }
    }

    // epilogue: per-edge scalar partial over this block's 160 h
    int eloc = (w << 4) + lane16;
    int e = e0 + eloc;
    int be = eb[e];
    const float* insb = instr + (size_t)be * H;
    float part = 0.f;
#pragma unroll
    for (int ht = 0; ht < NHT; ++ht) {
        int hb = hz * HH + ht * 16 + (g << 2);
#pragma unroll
        for (int r = 0; r < 4; ++r) {
            int h = hb + r;
            if (h < H) part += wrel[h] * eluf(insb[h] * acc[ht][r]);
        }
    }
    part += __shfl_xor(part, 16, 64);
    part += __shfl_xor(part, 32, 64);
    if (l < 16) atomicAdd(&rlog[ei[E + e]], dist[ei[e]] * part);
}

// ---- K6: per-batch segment softmax x2 + blend -> next_distribution
__global__ void k_final(const float* __restrict__ slog, const float* __restrict__ rlog,
                        const float* __restrict__ prop_sim, const int* __restrict__ offsets,
                        float* __restrict__ out)
{
    int b = blockIdx.x;
    int s0 = offsets[b], e1 = offsets[b + 1];
    int t = threadIdx.x, wave = t >> 6, lane = t & 63;
    __shared__ float shA[4], shB[4];
    float mS = -3.0e38f, mR = -3.0e38f;
    for (int i = s0 + t; i < e1; i += 256) {
        mS = fmaxf(mS, slog[i]);
        mR = fmaxf(mR, rlog[i]);
    }
    mS = wmax64(mS); mR = wmax64(mR);
    if (lane == 0) { shA[wave] = mS; shB[wave] = mR; }
    __syncthreads();
    mS = fmaxf(fmaxf(shA[0], shA[1]), fmaxf(shA[2], shA[3]));
    mR = fmaxf(fmaxf(shB[0], shB[1]), fmaxf(shB[2], shB[3]));
    __syncthreads();
    float sS = 0.f, sR = 0.f;
    for (int i = s0 + t; i < e1; i += 256) {
        sS += expf(slog[i] - mS);
        sR += expf(rlog[i] - mR);
    }
    sS = wsum64(sS); sR = wsum64(sR);
    if (lane == 0) { shA[wave] = sS; shB[wave] = sR; }
    __syncthreads();
    sS = shA[0] + shA[1] + shA[2] + shA[3];
    sR = shB[0] + shB[1] + shB[2] + shB[3];
    float r = prop_sim[b * PP + (PP - 1)];
    float iS = 1.f / sS, iR = 1.f / sR;
    for (int i = s0 + t; i < e1; i += 256) {
        float ns = expf(slog[i] - mS) * iS;
        float nr = expf(rlog[i] - mR) * iR;
        out[i] = r * nr + (1.f - r) * ns;
    }
}

extern "C" void kernel_launch(void* const* d_in, const int* in_sizes, int n_in,
                              void* d_out, int out_size, void* d_ws, size_t ws_size,
                              hipStream_t stream) {
    (void)n_in; (void)out_size; (void)ws_size;
    const float* instruction  = (const float*)d_in[0];
    const float* distribution = (const float*)d_in[1];
    const float* node_attrs   = (const float*)d_in[2];
    const float* edge_attrs   = (const float*)d_in[3];
    const int*   node_indices = (const int*)d_in[4];
    const int*   edge_batch   = (const int*)d_in[5];
    const int*   edge_indices = (const int*)d_in[6];
    const float* prop_embeds  = (const float*)d_in[7];
    const float* Ws           = (const float*)d_in[8];
    const float* W_state      = (const float*)d_in[9];
    const float* W_rel        = (const float*)d_in[10];

    int B = in_sizes[0] / H;   // 256
    int N = in_sizes[1];       // 51200
    int E = in_sizes[5];       // 102400

    float* out = (float*)d_out;        // [0,N): next_distribution, [N,N+B*PP): prop_sim
    float* prop_sim = out + N;

    float* ws = (float*)d_ws;
    float* state_logits = ws;                          // N
    float* rel_logits   = ws + N;                      // N
    int*   offsets      = (int*)(ws + 2 * (size_t)N);  // B+1
    int*   counts       = offsets + (B + 1);           // B
    uintptr_t wsp = (uintptr_t)(counts + B);
    wsp = (wsp + 15) & ~(uintptr_t)15;
    unsigned short* Whi = (unsigned short*)wsp;        // 300*320 bf16
    unsigned short* Wlo = Whi + (size_t)H * KP;

    size_t zero_bytes = (size_t)2 * N * sizeof(float) + (size_t)(2 * B + 1) * sizeof(int);
    hipMemsetAsync(d_ws, 0, zero_bytes, stream);

    k_presplit<<<H, KP, 0, stream>>>(Ws + 4 * (size_t)H * H, Whi, Wlo);
    k_prop_sim<<<B, 64, 0, stream>>>(instruction, prop_embeds, prop_sim);
    k_counts<<<(N + 255) / 256, 256, 0, stream>>>(node_indices, counts, N);
    k_scan<<<1, 256, 0, stream>>>(counts, offsets, B);
    k_node<<<dim3(6, B, 2), NTHREADS, 0, stream>>>(node_attrs, Ws, instruction, prop_sim,
                                                   W_state, offsets, state_logits, N);
    k_edge<<<dim3(E / NE, 2), NTHREADS, 0, stream>>>(edge_attrs, Whi, Wlo, instruction,
                                                     W_rel, edge_batch, edge_indices,
                                                     distribution, rel_logits, E);
    k_final<<<B, 256, 0, stream>>>(state_logits, rel_logits, prop_sim, offsets, out);
}

// Round 6
// 366.123 us; speedup vs baseline: 6.0892x; 1.1675x over previous
//
#include <hip/hip_runtime.h>
#include <math.h>

#define H 300
#define PP 5
#define NE 64          // rows (edges/nodes) per block tile
#define KC 32          // k per chunk (bf16)
#define NCH 10         // 320 / 32
#define WROWS 320      // padded h rows in W tile
#define ROWB 128       // bytes per LDS row: [hi 64B | lo 64B]
#define WTILE (WROWS * ROWB)   // 40960 B
#define ATILE (NE * ROWB)      // 8192 B
#define NTHREADS 256

using short8 = __attribute__((ext_vector_type(8))) short;
using f32x4  = __attribute__((ext_vector_type(4))) float;

__device__ __forceinline__ float wsum64(float v) {
#pragma unroll
    for (int m = 32; m >= 1; m >>= 1) v += __shfl_xor(v, m, 64);
    return v;
}
__device__ __forceinline__ float wmax64(float v) {
#pragma unroll
    for (int m = 32; m >= 1; m >>= 1) v = fmaxf(v, __shfl_xor(v, m, 64));
    return v;
}
__device__ __forceinline__ float eluf(float x) { return x > 0.f ? x : expm1f(x); }

__device__ __forceinline__ unsigned short f2bf(float x) {
    unsigned int u = __float_as_uint(x);
    unsigned int r = u + 0x7FFF + ((u >> 16) & 1);
    return (unsigned short)(r >> 16);
}
__device__ __forceinline__ float bf2f(unsigned short h) {
    return __uint_as_float(((unsigned int)h) << 16);
}
// swizzled byte offset within a [rows][128B] LDS tile (hi|lo interleaved rows)
__device__ __forceinline__ int sw(int r, int kb) {
    return r * ROWB + (kb ^ ((r & 7) << 4));
}
__device__ __forceinline__ void split4(const float* v, uint2& ph, uint2& pl) {
    unsigned short hs[4], ls[4];
#pragma unroll
    for (int i = 0; i < 4; ++i) {
        hs[i] = f2bf(v[i]);
        ls[i] = f2bf(v[i] - bf2f(hs[i]));
    }
    ph = make_uint2((unsigned)hs[0] | ((unsigned)hs[1] << 16),
                    (unsigned)hs[2] | ((unsigned)hs[3] << 16));
    pl = make_uint2((unsigned)ls[0] | ((unsigned)ls[1] << 16),
                    (unsigned)ls[2] | ((unsigned)ls[3] << 16));
}
// async global->LDS 16B copy (dest = wave-uniform base + lane*16)
__device__ __forceinline__ void gload16(const void* g, void* lds) {
    __builtin_amdgcn_global_load_lds(
        (const __attribute__((address_space(1))) unsigned int*)g,
        (__attribute__((address_space(3))) unsigned int*)lds, 16, 0, 0);
}

// ---- K1: prop_sim = softmax(instruction @ prop_embeds^T) ; grid=B, block=64
__global__ void k_prop_sim(const float* __restrict__ instr,
                           const float* __restrict__ pe,
                           float* __restrict__ prop_sim) {
    int b = blockIdx.x, lane = threadIdx.x;
    float dots[PP];
#pragma unroll
    for (int p = 0; p < PP; ++p) {
        float s = 0.f;
        for (int hh = lane; hh < H; hh += 64) s += instr[b * H + hh] * pe[p * H + hh];
        dots[p] = wsum64(s);
    }
    if (lane == 0) {
        float m = dots[0];
#pragma unroll
        for (int p = 1; p < PP; ++p) m = fmaxf(m, dots[p]);
        float e[PP], s = 0.f;
#pragma unroll
        for (int p = 0; p < PP; ++p) { e[p] = expf(dots[p] - m); s += e[p]; }
        float inv = 1.f / s;
#pragma unroll
        for (int p = 0; p < PP; ++p) prop_sim[b * PP + p] = e[p] * inv;
    }
}

// ---- K2: histogram of node_indices
__global__ void k_counts(const int* __restrict__ idx, int* __restrict__ counts, int N) {
    int i = blockIdx.x * blockDim.x + threadIdx.x;
    if (i < N) atomicAdd(&counts[idx[i]], 1);
}

// ---- K3: exclusive scan -> segment offsets (B<=256), 1 block of 256
__global__ void k_scan(const int* __restrict__ counts, int* __restrict__ offsets, int B) {
    __shared__ int sh[256];
    int t = threadIdx.x;
    int c = (t < B) ? counts[t] : 0;
    sh[t] = c;
    __syncthreads();
    for (int off = 1; off < 256; off <<= 1) {
        int v = (t >= off) ? sh[t - off] : 0;
        __syncthreads();
        sh[t] += v;
        __syncthreads();
    }
    if (t < B) offsets[t] = sh[t] - c;
    if (t == B - 1) offsets[B] = sh[t];
}

// ---- P1: static edge-W (Ws[4]) -> pre-swizzled bf16 hi/lo LDS image
// grid (NCH, 10), block 256. Image: [c][320 rows][128B].
__global__ void k_presplit(const float* __restrict__ W4, char* __restrict__ img) {
    int c = blockIdx.x;
    int idx = blockIdx.y * NTHREADS + threadIdx.x;   // [0, 2560)
    int r = idx >> 3, j = idx & 7;
    int k = c * KC + j * 4;
    float v[4] = {0.f, 0.f, 0.f, 0.f};
    if (r < H && k < H) *(float4*)v = *(const float4*)&W4[(size_t)r * H + k];
    uint2 ph, pl;
    split4(v, ph, pl);
    char* row = img + (size_t)c * WTILE + (size_t)r * ROWB;
    int x = (r & 7) << 4;
    *(uint2*)(row + ((j * 8) ^ x)) = ph;
    *(uint2*)(row + ((64 + j * 8) ^ x)) = pl;
}

// ---- P2: per-batch combined node-W -> pre-swizzled bf16 hi/lo LDS image
// grid (B, NCH), block 256, 10 jobs/thread. Image: [b][c][320][128B].
__global__ void k_combine(const float* __restrict__ Ws,
                          const float* __restrict__ prop_sim,
                          char* __restrict__ img) {
    int b = blockIdx.x, c = blockIdx.y, t = threadIdx.x;
    float ps0 = prop_sim[b * PP + 0], ps1 = prop_sim[b * PP + 1];
    float ps2 = prop_sim[b * PP + 2], ps3 = prop_sim[b * PP + 3];
    char* tile = img + ((size_t)b * NCH + c) * WTILE;
#pragma unroll
    for (int i = 0; i < 10; ++i) {
        int idx = t + i * NTHREADS;                  // [0, 2560)
        int r = idx >> 3, j = idx & 7;
        int k = c * KC + j * 4;
        float cv[4] = {0.f, 0.f, 0.f, 0.f};
        if (r < H && k < H) {
            size_t base = (size_t)r * H + k;
            float w0[4], w1[4], w2[4], w3[4];
            *(float4*)w0 = *(const float4*)&Ws[0 * (size_t)H * H + base];
            *(float4*)w1 = *(const float4*)&Ws[1 * (size_t)H * H + base];
            *(float4*)w2 = *(const float4*)&Ws[2 * (size_t)H * H + base];
            *(float4*)w3 = *(const float4*)&Ws[3 * (size_t)H * H + base];
#pragma unroll
            for (int q = 0; q < 4; ++q)
                cv[q] = fmaf(ps0, w0[q], fmaf(ps1, w1[q], fmaf(ps2, w2[q], ps3 * w3[q])));
        }
        uint2 ph, pl;
        split4(cv, ph, pl);
        char* row = tile + (size_t)r * ROWB;
        int x = (r & 7) << 4;
        *(uint2*)(row + ((j * 8) ^ x)) = ph;
        *(uint2*)(row + ((64 + j * 8) ^ x)) = pl;
    }
}

// ======================= MFMA node GEMM =======================
// grid (6, B). Block: 64 nodes x 300 h. 4 waves: wn=w&1 (32 cols), wh=w>>1 (160 h).
__global__ __launch_bounds__(NTHREADS, 3) void k_node(
    const float* __restrict__ na, const char* __restrict__ Wimg,
    const float* __restrict__ instr, const float* __restrict__ wstate,
    const int* __restrict__ offsets, float* __restrict__ slog, int N)
{
    __shared__ __align__(16) char W_t[WTILE];   // 40 KB
    __shared__ __align__(16) char A_t[ATILE];   // 8 KB

    int b = blockIdx.y;
    int start = offsets[b], end = offsets[b + 1];
    int n0 = start + blockIdx.x * NE;
    if (n0 >= end) return;
    int nn = min(NE, end - n0);

    int t = threadIdx.x;
    int w = t >> 6, l = t & 63, lane16 = l & 15, g = l >> 4;
    int wn = w & 1, wh = w >> 1;
    const char* Wsrc = Wimg + (size_t)b * NCH * WTILE;

    f32x4 acc[10][2];
#pragma unroll
    for (int ht = 0; ht < 10; ++ht)
#pragma unroll
        for (int cg = 0; cg < 2; ++cg) acc[ht][cg] = (f32x4){0.f, 0.f, 0.f, 0.f};

    float4 pa[2];
    auto loadA = [&](int c) {
#pragma unroll
        for (int i = 0; i < 2; ++i) {
            int idx = t + i * NTHREADS;              // [0, 512)
            int r = idx >> 3, j = idx & 7;
            int k = c * KC + j * 4;
            float4 v = {0.f, 0.f, 0.f, 0.f};
            if (k < H) {
                int row = min(n0 + r, N - 1);
                v = *(const float4*)&na[(size_t)row * H + k];
            }
            pa[i] = v;
        }
    };
    auto storeA = [&]() {
#pragma unroll
        for (int i = 0; i < 2; ++i) {
            int idx = t + i * NTHREADS;
            int r = idx >> 3, j = idx & 7;
            float v[4] = {pa[i].x, pa[i].y, pa[i].z, pa[i].w};
            uint2 ph, pl;
            split4(v, ph, pl);
            *(uint2*)(A_t + sw(r, j * 8)) = ph;
            *(uint2*)(A_t + sw(r, 64 + j * 8)) = pl;
        }
    };
    auto gloadW = [&](int c) {
        const char* src = Wsrc + (size_t)c * WTILE;
        int off0 = (t >> 6) * 1024 + (t & 63) * 16;
        int loff0 = (t >> 6) * 1024;
#pragma unroll
        for (int s = 0; s < 10; ++s)
            gload16(src + s * 4096 + off0, W_t + s * 4096 + loff0);
    };

    loadA(0);
    storeA();
    gloadW(0);
    loadA(1);
    __syncthreads();

    for (int c = 0; c < NCH; ++c) {
        // ---- compute chunk c ----
        short8 bh[2], bl[2];
#pragma unroll
        for (int cg = 0; cg < 2; ++cg) {
            int brow = wn * 32 + cg * 16 + lane16;
            bh[cg] = *(const short8*)(A_t + sw(brow, g * 16));
            bl[cg] = *(const short8*)(A_t + sw(brow, 64 + g * 16));
        }
#pragma unroll
        for (int ht = 0; ht < 10; ++ht) {
            int arow = (wh * 10 + ht) * 16 + lane16;
            short8 ah = *(const short8*)(W_t + sw(arow, g * 16));
            short8 al = *(const short8*)(W_t + sw(arow, 64 + g * 16));
#pragma unroll
            for (int cg = 0; cg < 2; ++cg) {
                acc[ht][cg] = __builtin_amdgcn_mfma_f32_16x16x32_bf16(ah, bh[cg], acc[ht][cg], 0, 0, 0);
                acc[ht][cg] = __builtin_amdgcn_mfma_f32_16x16x32_bf16(ah, bl[cg], acc[ht][cg], 0, 0, 0);
                acc[ht][cg] = __builtin_amdgcn_mfma_f32_16x16x32_bf16(al, bh[cg], acc[ht][cg], 0, 0, 0);
            }
        }
        if (c + 1 < NCH) {
            __syncthreads();
            storeA();
            gloadW(c + 1);
            if (c + 2 < NCH) loadA(c + 2);
            __syncthreads();
        }
    }

    // epilogue: partial logit over this wave's 160 h, for 32 cols
    const float* insb = instr + (size_t)b * H;
#pragma unroll
    for (int cg = 0; cg < 2; ++cg) {
        float part = 0.f;
#pragma unroll
        for (int ht = 0; ht < 10; ++ht) {
            int hb = wh * 160 + ht * 16 + g * 4;
#pragma unroll
            for (int r = 0; r < 4; ++r) {
                int h = hb + r;
                if (h < H) part += wstate[h] * eluf(insb[h] * acc[ht][cg][r]);
            }
        }
        part += __shfl_xor(part, 16, 64);
        part += __shfl_xor(part, 32, 64);
        int col = wn * 32 + cg * 16 + lane16;
        if (l < 16 && col < nn) atomicAdd(&slog[n0 + col], part);
    }
}

// ======================= MFMA edge GEMM =======================
// grid (E/64). Same structure; static W image; per-edge scatter epilogue.
__global__ __launch_bounds__(NTHREADS, 3) void k_edge(
    const float* __restrict__ ea, const char* __restrict__ Wimg,
    const float* __restrict__ instr, const float* __restrict__ wrel,
    const int* __restrict__ eb, const int* __restrict__ ei,
    const float* __restrict__ dist, float* __restrict__ rlog, int E)
{
    __shared__ __align__(16) char W_t[WTILE];
    __shared__ __align__(16) char A_t[ATILE];

    int e0 = blockIdx.x * NE;
    int t = threadIdx.x;
    int w = t >> 6, l = t & 63, lane16 = l & 15, g = l >> 4;
    int wn = w & 1, wh = w >> 1;

    f32x4 acc[10][2];
#pragma unroll
    for (int ht = 0; ht < 10; ++ht)
#pragma unroll
        for (int cg = 0; cg < 2; ++cg) acc[ht][cg] = (f32x4){0.f, 0.f, 0.f, 0.f};

    float4 pa[2];
    auto loadA = [&](int c) {
#pragma unroll
        for (int i = 0; i < 2; ++i) {
            int idx = t + i * NTHREADS;
            int r = idx >> 3, j = idx & 7;
            int k = c * KC + j * 4;
            float4 v = {0.f, 0.f, 0.f, 0.f};
            if (k < H) v = *(const float4*)&ea[(size_t)(e0 + r) * H + k];
            pa[i] = v;
        }
    };
    auto storeA = [&]() {
#pragma unroll
        for (int i = 0; i < 2; ++i) {
            int idx = t + i * NTHREADS;
            int r = idx >> 3, j = idx & 7;
            float v[4] = {pa[i].x, pa[i].y, pa[i].z, pa[i].w};
            uint2 ph, pl;
            split4(v, ph, pl);
            *(uint2*)(A_t + sw(r, j * 8)) = ph;
            *(uint2*)(A_t + sw(r, 64 + j * 8)) = pl;
        }
    };
    auto gloadW = [&](int c) {
        const char* src = Wimg + (size_t)c * WTILE;
        int off0 = (t >> 6) * 1024 + (t & 63) * 16;
        int loff0 = (t >> 6) * 1024;
#pragma unroll
        for (int s = 0; s < 10; ++s)
            gload16(src + s * 4096 + off0, W_t + s * 4096 + loff0);
    };

    loadA(0);
    storeA();
    gloadW(0);
    loadA(1);
    __syncthreads();

    for (int c = 0; c < NCH; ++c) {
        short8 bh[2], bl[2];
#pragma unroll
        for (int cg = 0; cg < 2; ++cg) {
            int brow = wn * 32 + cg * 16 + lane16;
            bh[cg] = *(const short8*)(A_t + sw(brow, g * 16));
            bl[cg] = *(const short8*)(A_t + sw(brow, 64 + g * 16));
        }
#pragma unroll
        for (int ht = 0; ht < 10; ++ht) {
            int arow = (wh * 10 + ht) * 16 + lane16;
            short8 ah = *(const short8*)(W_t + sw(arow, g * 16));
            short8 al = *(const short8*)(W_t + sw(arow, 64 + g * 16));
#pragma unroll
            for (int cg = 0; cg < 2; ++cg) {
                acc[ht][cg] = __builtin_amdgcn_mfma_f32_16x16x32_bf16(ah, bh[cg], acc[ht][cg], 0, 0, 0);
                acc[ht][cg] = __builtin_amdgcn_mfma_f32_16x16x32_bf16(ah, bl[cg], acc[ht][cg], 0, 0, 0);
                acc[ht][cg] = __builtin_amdgcn_mfma_f32_16x16x32_bf16(al, bh[cg], acc[ht][cg], 0, 0, 0);
            }
        }
        if (c + 1 < NCH) {
            __syncthreads();
            storeA();
            gloadW(c + 1);
            if (c + 2 < NCH) loadA(c + 2);
            __syncthreads();
        }
    }

    // epilogue: per-edge scalar partial over this wave's 160 h
#pragma unroll
    for (int cg = 0; cg < 2; ++cg) {
        int e = e0 + wn * 32 + cg * 16 + lane16;
        int be = eb[e];
        const float* insb = instr + (size_t)be * H;
        float part = 0.f;
#pragma unroll
        for (int ht = 0; ht < 10; ++ht) {
            int hb = wh * 160 + ht * 16 + g * 4;
#pragma unroll
            for (int r = 0; r < 4; ++r) {
                int h = hb + r;
                if (h < H) part += wrel[h] * eluf(insb[h] * acc[ht][cg][r]);
            }
        }
        part += __shfl_xor(part, 16, 64);
        part += __shfl_xor(part, 32, 64);
        if (l < 16) atomicAdd(&rlog[ei[E + e]], dist[ei[e]] * part);
    }
}

// ---- K6: per-batch segment softmax x2 + blend -> next_distribution
__global__ void k_final(const float* __restrict__ slog, const float* __restrict__ rlog,
                        const float* __restrict__ prop_sim, const int* __restrict__ offsets,
                        float* __restrict__ out)
{
    int b = blockIdx.x;
    int s0 = offsets[b], e1 = offsets[b + 1];
    int t = threadIdx.x, wave = t >> 6, lane = t & 63;
    __shared__ float shA[4], shB[4];
    float mS = -3.0e38f, mR = -3.0e38f;
    for (int i = s0 + t; i < e1; i += 256) {
        mS = fmaxf(mS, slog[i]);
        mR = fmaxf(mR, rlog[i]);
    }
    mS = wmax64(mS); mR = wmax64(mR);
    if (lane == 0) { shA[wave] = mS; shB[wave] = mR; }
    __syncthreads();
    mS = fmaxf(fmaxf(shA[0], shA[1]), fmaxf(shA[2], shA[3]));
    mR = fmaxf(fmaxf(shB[0], shB[1]), fmaxf(shB[2], shB[3]));
    __syncthreads();
    float sS = 0.f, sR = 0.f;
    for (int i = s0 + t; i < e1; i += 256) {
        sS += expf(slog[i] - mS);
        sR += expf(rlog[i] - mR);
    }
    sS = wsum64(sS); sR = wsum64(sR);
    if (lane == 0) { shA[wave] = sS; shB[wave] = sR; }
    __syncthreads();
    sS = shA[0] + shA[1] + shA[2] + shA[3];
    sR = shB[0] + shB[1] + shB[2] + shB[3];
    float r = prop_sim[b * PP + (PP - 1)];
    float iS = 1.f / sS, iR = 1.f / sR;
    for (int i = s0 + t; i < e1; i += 256) {
        float ns = expf(slog[i] - mS) * iS;
        float nr = expf(rlog[i] - mR) * iR;
        out[i] = r * nr + (1.f - r) * ns;
    }
}

extern "C" void kernel_launch(void* const* d_in, const int* in_sizes, int n_in,
                              void* d_out, int out_size, void* d_ws, size_t ws_size,
                              hipStream_t stream) {
    (void)n_in; (void)out_size; (void)ws_size;
    const float* instruction  = (const float*)d_in[0];
    const float* distribution = (const float*)d_in[1];
    const float* node_attrs   = (const float*)d_in[2];
    const float* edge_attrs   = (const float*)d_in[3];
    const int*   node_indices = (const int*)d_in[4];
    const int*   edge_batch   = (const int*)d_in[5];
    const int*   edge_indices = (const int*)d_in[6];
    const float* prop_embeds  = (const float*)d_in[7];
    const float* Ws           = (const float*)d_in[8];
    const float* W_state      = (const float*)d_in[9];
    const float* W_rel        = (const float*)d_in[10];

    int B = in_sizes[0] / H;   // 256
    int N = in_sizes[1];       // 51200
    int E = in_sizes[5];       // 102400

    float* out = (float*)d_out;        // [0,N): next_distribution, [N,N+B*PP): prop_sim
    float* prop_sim = out + N;

    float* ws = (float*)d_ws;
    float* state_logits = ws;                          // N
    float* rel_logits   = ws + N;                      // N
    int*   offsets      = (int*)(ws + 2 * (size_t)N);  // B+1
    int*   counts       = offsets + (B + 1);           // B
    uintptr_t wsp = (uintptr_t)(counts + B);
    wsp = (wsp + 255) & ~(uintptr_t)255;
    char* Wr_img = (char*)wsp;                         // NCH*WTILE = 409600 B
    char* Wc_img = Wr_img + (size_t)NCH * WTILE;       // B*NCH*WTILE = 104.86 MB

    size_t zero_bytes = (size_t)2 * N * sizeof(float) + (size_t)(2 * B + 1) * sizeof(int);
    hipMemsetAsync(d_ws, 0, zero_bytes, stream);

    k_prop_sim<<<B, 64, 0, stream>>>(instruction, prop_embeds, prop_sim);
    k_presplit<<<dim3(NCH, 10), NTHREADS, 0, stream>>>(Ws + 4 * (size_t)H * H, Wr_img);
    k_counts<<<(N + 255) / 256, 256, 0, stream>>>(node_indices, counts, N);
    k_scan<<<1, 256, 0, stream>>>(counts, offsets, B);
    k_combine<<<dim3(B, NCH), NTHREADS, 0, stream>>>(Ws, prop_sim, Wc_img);
    k_node<<<dim3(6, B), NTHREADS, 0, stream>>>(node_attrs, Wc_img, instruction,
                                                W_state, offsets, state_logits, N);
    k_edge<<<E / NE, NTHREADS, 0, stream>>>(edge_attrs, Wr_img, instruction, W_rel,
                                            edge_batch, edge_indices,
                                            distribution, rel_logits, E);
    k_final<<<B, 256, 0, stream>>>(state_logits, rel_logits, prop_sim, offsets, out);
}